// Round 10
// baseline (449.499 us; speedup 1.0000x reference)
//
#include <hip/hip_runtime.h>
#include <stdint.h>

// ---------------------------------------------------------------------------
// DeltaNet (gated delta rule) forward, MI355X gfx950. Round 22.
// Round 21: 401us (phaseB LDS-shared M, 4 cols/block: -20us). Note: phaseA
// (identical r13 code) measured 119.6 vs 107 in earlier sessions -> ~10%
// cross-session clock drift; only within-session deltas are trustworthy.
// This round: phaseB v3 — 8 cols/block (2 waves x 4 cols/wave), M chunk
// still LDS-staged once + dbuf prefetch: M traffic 256 -> 134 MB. Chain
// grows (80 b128/chunk) but BW halves; predicted phaseB ~43 -> ~28us.
// Per-column math/order identical -> bit-exact (absmax 0.04296875).
// P column map: [0,1024) q | [1024,3072) k | [3072,5120) v |
//   [5120,5152) beta-pre | [5152,5168) a-pre | [5168,6192) gate | pad
// ---------------------------------------------------------------------------

typedef unsigned short u16;
typedef __attribute__((ext_vector_type(8))) short bf16x8;
typedef __attribute__((ext_vector_type(4))) float f32x4;
typedef __attribute__((ext_vector_type(2))) float f32x2;
typedef __attribute__((ext_vector_type(4))) unsigned short u16x4;

#define TT 2048
#define NP 6208
#define NC 64
#define CS 64

__device__ __forceinline__ u16 f2bf(float f) {
  union { float f; uint32_t u; } v; v.f = f;
  uint32_t r = v.u + 0x7fffu + ((v.u >> 16) & 1u);  // RNE
  return (u16)(r >> 16);
}
__device__ __forceinline__ float bf2f(u16 b) {
  union { uint32_t u; float f; } v; v.u = ((uint32_t)b) << 16; return v.f;
}

// async global->LDS, 16B per lane; LDS dest = wave-uniform base + lane*16
__device__ __forceinline__ void gload_lds16(const u16* g, u16* l) {
  __builtin_amdgcn_global_load_lds(
      (__attribute__((address_space(1))) const void*)(uintptr_t)g,
      (__attribute__((address_space(3))) void*)(uint32_t)(uintptr_t)l, 16, 0, 0);
}

__global__ void cvt_kernel(const float* __restrict__ src, u16* __restrict__ dst, long n) {
  long i = (long)blockIdx.x * 256 + threadIdx.x;
  if (i < n) dst[i] = f2bf(src[i]);
}

// fused transpose+convert of all 7 weight matrices (rows always 1024)
__global__ __launch_bounds__(256) void transAll_kernel(
    const float* __restrict__ Wq, const float* __restrict__ Wk,
    const float* __restrict__ Wv, const float* __restrict__ Wb,
    const float* __restrict__ Wa, const float* __restrict__ Wg,
    const float* __restrict__ Wo, u16* __restrict__ WT, u16* __restrict__ WoT) {
  int bx = blockIdx.x;
  const float* src; u16* dst; int cols;
  if      (bx < 32)  { src = Wq; dst = WT;                cols = 1024; }
  else if (bx < 96)  { src = Wk; dst = WT + 1024UL*1024;  cols = 2048; bx -= 32; }
  else if (bx < 160) { src = Wv; dst = WT + 3072UL*1024;  cols = 2048; bx -= 96; }
  else if (bx < 161) { src = Wb; dst = WT + 5120UL*1024;  cols = 32;   bx -= 160; }
  else if (bx < 162) { src = Wa; dst = WT + 5152UL*1024;  cols = 16;   bx -= 161; }
  else if (bx < 194) { src = Wg; dst = WT + 5168UL*1024;  cols = 1024; bx -= 162; }
  else               { src = Wo; dst = WoT;               cols = 1024; bx -= 194; }
  __shared__ float tile[32][33];
  const int tx = threadIdx.x & 31, ty = threadIdx.x >> 5;
  const int c0 = bx * 32, r0 = blockIdx.y * 32;
  for (int rr = ty; rr < 32; rr += 8)
    if (c0 + tx < cols) tile[rr][tx] = src[(size_t)(r0 + rr) * cols + c0 + tx];
  __syncthreads();
  for (int rr = ty; rr < 32; rr += 8)
    if (c0 + rr < cols) dst[(size_t)(c0 + rr) * 1024 + r0 + tx] = f2bf(tile[tx][rr]);
}

__global__ __launch_bounds__(256) void beacon_kernel(float* __restrict__ out, int n) {
  int i = blockIdx.x * 256 + threadIdx.x;
  if (i < n) out[i] = 4000.0f;
}

// 128x128-tile GEMM: C = A[M,K](bf16,lda) * BT[N,K]^T(bf16, row stride K).
// 4 waves, each a 64x64 quadrant. BT must be zero-padded to grid.y*128 rows.
// Staging via global_load_lds (m97 structure, linear [128][32] LDS).
__global__ __launch_bounds__(256) void gemm128(const u16* __restrict__ A,
    const u16* __restrict__ BT, float* __restrict__ Cf, u16* __restrict__ Cb,
    int K, int lda, int ldc, int Nmax, int out_bf16) {
  const int bm = blockIdx.x * 128, bn = blockIdx.y * 128;
  const int tid = threadIdx.x, w = tid >> 6, lane = tid & 63;
  const int wr = (w >> 1) * 64, wc = (w & 1) * 64;
  const int quad = lane >> 4, r = lane & 15;
  __shared__ u16 As[128][32], Bs[128][32];   // linear: global_load_lds dest
  f32x4 acc[4][4] = {};
  // wave w stages rows w*32..w*32+31 (two 16-row instructions)
  const int sr = w * 32 + (lane >> 2);       // global row for inst 0
  const int sc = (lane & 3) * 8;             // u16 col offset within 32-wide tile
  const u16* gA0 = A  + (size_t)(bm + sr) * lda + sc;
  const u16* gA1 = A  + (size_t)(bm + sr + 16) * lda + sc;
  const u16* gB0 = BT + (size_t)(bn + sr) * K + sc;
  const u16* gB1 = BT + (size_t)(bn + sr + 16) * K + sc;
  u16* lA0 = &As[w * 32][0];
  u16* lA1 = &As[w * 32 + 16][0];
  u16* lB0 = &Bs[w * 32][0];
  u16* lB1 = &Bs[w * 32 + 16][0];
  for (int ks = 0; ks < K; ks += 32) {
    __syncthreads();   // prev-iter readers done before LDS overwrite
    gload_lds16(gA0 + ks, lA0);
    gload_lds16(gA1 + ks, lA1);
    gload_lds16(gB0 + ks, lB0);
    gload_lds16(gB1 + ks, lB1);
    __syncthreads();   // compiler drains vmcnt(0) before barrier
    bf16x8 af[4], bf[4];
#pragma unroll
    for (int i = 0; i < 4; i++) af[i] = *(const bf16x8*)&As[wr + i * 16 + r][quad * 8];
#pragma unroll
    for (int j = 0; j < 4; j++) bf[j] = *(const bf16x8*)&Bs[wc + j * 16 + r][quad * 8];
#pragma unroll
    for (int i = 0; i < 4; i++)
#pragma unroll
      for (int j = 0; j < 4; j++)
        acc[i][j] = __builtin_amdgcn_mfma_f32_16x16x32_bf16(af[i], bf[j], acc[i][j], 0, 0, 0);
  }
#pragma unroll
  for (int i = 0; i < 4; i++)
#pragma unroll
    for (int j = 0; j < 4; j++)
#pragma unroll
      for (int rg = 0; rg < 4; rg++) {
        int row = bm + wr + i * 16 + quad * 4 + rg;
        int col = bn + wc + j * 16 + r;
        if (col < Nmax) {
          float v = acc[i][j][rg];
          if (out_bf16) Cb[(size_t)row * ldc + col] = f2bf(v);
          else          Cf[(size_t)row * ldc + col] = v;
        }
      }
}

// 4 heads per block (one per wave); per-wave code identical to the old
// 64-thread block version (launch-overhead reduction only).
__global__ __launch_bounds__(256) void prep_kernel(float* __restrict__ P,
    const float* __restrict__ A_log, const float* __restrict__ dt_bias,
    float* __restrict__ betab, float* __restrict__ gbuf) {
  const int t = blockIdx.x >> 2, w = threadIdx.x >> 6, lane = threadIdx.x & 63;
  const int h = (blockIdx.x & 3) * 4 + w;
  float* Pt = P + (size_t)t * NP;
  float qv = Pt[h * 64 + lane];
  float ss = qv * qv;
#pragma unroll
  for (int off = 32; off; off >>= 1) ss += __shfl_xor(ss, off);
  Pt[h * 64 + lane] = qv * rsqrtf(ss + 1e-6f) * 0.125f;
#pragma unroll
  for (int nh = 0; nh < 2; nh++) {
    float kv = Pt[1024 + nh * 1024 + h * 64 + lane];
    float ks = kv * kv;
#pragma unroll
    for (int off = 32; off; off >>= 1) ks += __shfl_xor(ks, off);
    Pt[1024 + nh * 1024 + h * 64 + lane] = kv * rsqrtf(ks + 1e-6f);
  }
  if (lane < 2) {
    float bb = Pt[5120 + lane * 16 + h];
    betab[(size_t)(2 * t + lane) * 16 + h] = 2.f / (1.f + expf(-bb));
  }
  if (lane == 0) {
    float a = Pt[5152 + h] + dt_bias[h];
    float sp = (a > 20.f) ? a : log1pf(expf(a));
    gbuf[t * 16 + h] = -expf(A_log[h]) * sp;
  }
}

// phase A: per (c,h): G, T, W(bf16), M(fp32), Uv(bf16), NT(fp32), cum.
// 3 LDS arrays (53248 B -> 3 blocks/CU): LA: kT->Tt->Uv, LB: kf, LC: Sc->v->W.
// (r13 version verbatim; all MFMA/fusion/reg-carry variants measured worse)
__global__ __launch_bounds__(256, 1) void phaseA_kernel(const float* __restrict__ P,
    const float* __restrict__ betab, const float* __restrict__ gbuf,
    u16* __restrict__ Wbuf, u16* __restrict__ Uvbuf,
    float* __restrict__ Mbuf, float* __restrict__ NTbuf, float* __restrict__ cumbuf) {
  const int c = blockIdx.x, h = blockIdx.y, tid = threadIdx.x;
  const int bi = tid >> 4, bj = tid & 15;
  __shared__ float LA[64][68];   // kT -> Tt -> Uv
  __shared__ float LB[64][68];   // kf (persistent)
  __shared__ float LC[64][68];   // Sc -> v -> W
  __shared__ float cumch[64], betach[64], bbch[64], rowfl[64];
  const size_t base = ((size_t)c * 16 + h) * 4096;

  for (int e = tid; e < 4096; e += 256) {
    int i = e >> 6, d = e & 63, s = c * 64 + i, t = s >> 1, nh = s & 1;
    float kv = P[(size_t)t * NP + 1024 + nh * 1024 + h * 64 + d];
    LB[i][d] = kv; LA[d][i] = kv;
  }
  if (tid < 64) betach[tid] = betab[(size_t)(c * 64 + tid) * 16 + h];
  __syncthreads();
  if (tid == 0) {
    float cum = 0.f;
    for (int i = 0; i < 64; i++) {
      if ((i & 1) == 0) cum += gbuf[(c * 32 + (i >> 1)) * 16 + h];
      cumch[i] = cum;
    }
  }
  __syncthreads();
  if (tid < 64) {
    bbch[tid] = betach[tid] * expf(cumch[tid]);
    rowfl[tid] = expf(cumch[63] - cumch[tid]);
  }
  // G then scale -> LC
  {
    float acc[4][4] = {};
#pragma unroll 4
    for (int d = 0; d < 64; d++) {
      f32x4 a = *(const f32x4*)&LA[d][4 * bi];
      f32x4 b = *(const f32x4*)&LA[d][4 * bj];
#pragma unroll
      for (int rr = 0; rr < 4; rr++)
#pragma unroll
        for (int cc = 0; cc < 4; cc++) acc[rr][cc] += a[rr] * b[cc];
    }
#pragma unroll
    for (int rr = 0; rr < 4; rr++)
#pragma unroll
      for (int cc = 0; cc < 4; cc++) {
        int i = 4 * bi + rr, j = 4 * bj + cc;
        LC[i][j] = (j < i) ? betach[i] * expf(cumch[i] - cumch[j]) * acc[rr][cc] : 0.f;
      }
  }
  __syncthreads();
  // T = (I+A)^-1 forward substitution: LC(Sc) -> LA[j][i] (Tt)
  {
    int col = tid >> 2, part = tid & 3;
    if (part == 0) LA[col][0] = (col == 0) ? 1.f : 0.f;
    for (int i = 1; i < 64; i++) {
      float partial = 0.f;
      for (int j = col + part; j < i; j += 4) partial += LC[i][j] * LA[col][j];
      partial += __shfl_xor(partial, 1);
      partial += __shfl_xor(partial, 2);
      if (part == 0) LA[col][i] = ((i == col) ? 1.f : 0.f) - partial;
    }
  }
  __syncthreads();
  // prefetch v into regs now; ds_write after M (latency hides under W+M)
  float vreg[16];
  {
    const int vi = tid >> 6, vd = tid & 63;
#pragma unroll
    for (int s = 0; s < 16; s++) {
      int i = vi + 4 * s, ss = c * 64 + i, t = ss >> 1, nh = ss & 1;
      vreg[s] = P[(size_t)t * NP + 3072 + nh * 1024 + h * 64 + vd];
    }
  }
  // W[i][d] = sum_{j<=i} T[i][j]*bb[j]*k[j][d]  (triangular trip)
  {
    float acc[4][4] = {};
#pragma unroll 4
    for (int j = 0; j < 4 * bi + 4; j++) {
      f32x4 tv = *(const f32x4*)&LA[j][4 * bi];
      f32x4 kv = *(const f32x4*)&LB[j][4 * bj];
      float bbj = bbch[j];
#pragma unroll
      for (int rr = 0; rr < 4; rr++)
#pragma unroll
        for (int cc = 0; cc < 4; cc++) acc[rr][cc] += tv[rr] * bbj * kv[cc];
    }
#pragma unroll
    for (int rr = 0; rr < 4; rr++) {
      int i = 4 * bi + rr;
      u16x4 wb;
#pragma unroll
      for (int cc = 0; cc < 4; cc++) { LC[i][4 * bj + cc] = acc[rr][cc]; wb[cc] = f2bf(acc[rr][cc]); }
      *(u16x4*)&Wbuf[base + (size_t)i * 64 + 4 * bj] = wb;
    }
  }
  __syncthreads();
  // M[m][mm] = bL*delta - sum_i rowf[i]*k[i][m]*W[i][mm]
  {
    const float bL = expf(cumch[63]);
    float acc[4][4] = {};
#pragma unroll 4
    for (int i = 0; i < 64; i++) {
      f32x4 kv = *(const f32x4*)&LB[i][4 * bi];
      f32x4 wv = *(const f32x4*)&LC[i][4 * bj];
      float rf = rowfl[i];
#pragma unroll
      for (int rr = 0; rr < 4; rr++)
#pragma unroll
        for (int cc = 0; cc < 4; cc++) acc[rr][cc] += rf * kv[rr] * wv[cc];
    }
#pragma unroll
    for (int rr = 0; rr < 4; rr++) {
      int m = 4 * bi + rr;
      f32x4 mv;
#pragma unroll
      for (int cc = 0; cc < 4; cc++)
        mv[cc] = ((m == 4 * bj + cc) ? bL : 0.f) - acc[rr][cc];
      *(f32x4*)&Mbuf[base + (size_t)m * 64 + 4 * bj] = mv;
    }
  }
  __syncthreads();
  // stage v (from regs) over LC
  {
    const int vi = tid >> 6, vd = tid & 63;
#pragma unroll
    for (int s = 0; s < 16; s++) LC[vi + 4 * s][vd] = vreg[s];
  }
  __syncthreads();
  // Uv[i][d] = sum_{j<=i} T[i][j]*beta[j]*v[j][d] -> regs (LA still = Tt)
  float ua[4][4] = {};
  {
#pragma unroll 4
    for (int j = 0; j < 4 * bi + 4; j++) {
      f32x4 tv = *(const f32x4*)&LA[j][4 * bi];
      f32x4 vv = *(const f32x4*)&LC[j][4 * bj];
      float be = betach[j];
#pragma unroll
      for (int rr = 0; rr < 4; rr++)
#pragma unroll
        for (int cc = 0; cc < 4; cc++) ua[rr][cc] += tv[rr] * be * vv[cc];
    }
  }
  __syncthreads();   // all Tt reads complete before overwrite
  {
#pragma unroll
    for (int rr = 0; rr < 4; rr++) {
      int i = 4 * bi + rr;
      u16x4 ub;
#pragma unroll
      for (int cc = 0; cc < 4; cc++) { LA[i][4 * bj + cc] = ua[rr][cc]; ub[cc] = f2bf(ua[rr][cc]); }
      *(u16x4*)&Uvbuf[base + (size_t)i * 64 + 4 * bj] = ub;
    }
  }
  __syncthreads();
  // NT[d][m] = sum_i rowf[i]*k[i][m]*Uv[i][d]
  {
    float acc[4][4] = {};
#pragma unroll 4
    for (int i = 0; i < 64; i++) {
      f32x4 kv = *(const f32x4*)&LB[i][4 * bi];
      f32x4 uv = *(const f32x4*)&LA[i][4 * bj];
      float rf = rowfl[i];
#pragma unroll
      for (int rr = 0; rr < 4; rr++)
#pragma unroll
        for (int cc = 0; cc < 4; cc++) acc[rr][cc] += rf * kv[rr] * uv[cc];
    }
#pragma unroll
    for (int cc = 0; cc < 4; cc++) {
      f32x4 nv;
#pragma unroll
      for (int rr = 0; rr < 4; rr++) nv[rr] = acc[rr][cc];
      *(f32x4*)&NTbuf[base + (size_t)(4 * bj + cc) * 64 + 4 * bi] = nv;
    }
  }
  if (tid < 64) cumbuf[((size_t)c * 16 + h) * 64 + tid] = cumch[tid];
}

// phase B v3: 8 cols/block (2 waves x 4 cols/wave); M chunk LDS-staged once
// + dbuf prefetch (r21 structure, wider col groups): M traffic 256->134MB.
// Per-column math/order identical to r13/r21 (bit-exact).
__global__ __launch_bounds__(128) void phaseB_kernel(const float* __restrict__ Mbuf,
    const float* __restrict__ NTbuf, u16* __restrict__ S0Tbuf) {
  const int g = blockIdx.x, h = blockIdx.y;
  const int tid = threadIdx.x, wv = tid >> 6, l = tid & 63;
  const int cb = 8 * g + 4 * wv;   // this wave's 4 columns: cb..cb+3
  __shared__ float Ms[2][64][68];
  __shared__ float Ssh[2][8][64];
  float s[4] = {0.f, 0.f, 0.f, 0.f}, n[4];
  f32x4 mn[8];
  // stage chunk 0: thread t covers f32x4-slots t*8..t*8+7 (row=slot>>4, s=slot&15)
  {
    const float* Mc = Mbuf + (size_t)h * 4096;
#pragma unroll
    for (int i = 0; i < 8; i++) {
      int sl = tid * 8 + i;
      mn[i] = *(const f32x4*)(Mc + (sl >> 4) * 64 + (sl & 15) * 4);
    }
#pragma unroll
    for (int i = 0; i < 8; i++) {
      int sl = tid * 8 + i;
      *(f32x4*)&Ms[0][sl >> 4][(sl & 15) * 4] = mn[i];
    }
    const float* Nc = NTbuf + (size_t)h * 4096;
#pragma unroll
    for (int ci = 0; ci < 4; ci++) {
      n[ci] = Nc[(cb + ci) * 64 + l];
      Ssh[0][4 * wv + ci][l] = 0.f;
    }
  }
  __syncthreads();
  int p = 0;
  for (int c = 0; c < NC; c++) {
    const size_t base = ((size_t)c * 16 + h) * 4096;
#pragma unroll
    for (int ci = 0; ci < 4; ci++)
      S0Tbuf[base + (size_t)(cb + ci) * 64 + l] = f2bf(s[ci]);
    float nn[4] = {0.f, 0.f, 0.f, 0.f};
    if (c + 1 < NC) {
      // issue next-chunk M loads (latency hides under compute below)
      const float* Mn = Mbuf + ((size_t)(c + 1) * 16 + h) * 4096;
#pragma unroll
      for (int i = 0; i < 8; i++) {
        int sl = tid * 8 + i;
        mn[i] = *(const f32x4*)(Mn + (sl >> 4) * 64 + (sl & 15) * 4);
      }
      const float* Nn = NTbuf + ((size_t)(c + 1) * 16 + h) * 4096;
#pragma unroll
      for (int ci = 0; ci < 4; ci++) nn[ci] = Nn[(cb + ci) * 64 + l];
    }
    float acc[4];
#pragma unroll
    for (int ci = 0; ci < 4; ci++) acc[ci] = n[ci];
#pragma unroll
    for (int q = 0; q < 16; q++) {
      f32x4 mv = *(const f32x4*)&Ms[p][l][4 * q];
#pragma unroll
      for (int ci = 0; ci < 4; ci++) {
        f32x4 sv = *(const f32x4*)&Ssh[p][4 * wv + ci][4 * q];
#pragma unroll
        for (int t = 0; t < 4; t++) acc[ci] += mv[t] * sv[t];
      }
    }
#pragma unroll
    for (int ci = 0; ci < 4; ci++) { s[ci] = acc[ci]; Ssh[p ^ 1][4 * wv + ci][l] = s[ci]; }
    if (c + 1 < NC) {
#pragma unroll
      for (int i = 0; i < 8; i++) {
        int sl = tid * 8 + i;
        *(f32x4*)&Ms[p ^ 1][sl >> 4][(sl & 15) * 4] = mn[i];
      }
    }
    __syncthreads();
    p ^= 1;
#pragma unroll
    for (int ci = 0; ci < 4; ci++) n[ci] = nn[ci];
  }
}

// phase C (with phaseB2 fused in):
//   kTc: k -> S0 ; Ul: W^T -> U (U = Uv - W*S0). pass2 byte-identical.
__global__ __launch_bounds__(256) void phaseC_kernel(const float* __restrict__ P,
    const float* __restrict__ cumbuf, const u16* __restrict__ Wbuf,
    const u16* __restrict__ Uvbuf, const u16* __restrict__ S0Tbuf,
    const float* __restrict__ nw, u16* __restrict__ ybuf) {
  const int c = blockIdx.x, h = blockIdx.y, tid = threadIdx.x;
  const int rb = tid >> 4, jb = tid & 15;
  __shared__ float qT[64][36];    // [d][r]; reused as ol[32][68]
  __shared__ float kTc[64][68];   // k[d][j] -> S0l[m][d]
  __shared__ float Ul[64][68];    // WTl[m][i] -> U[j][d]
  __shared__ float PmT[64][36];
  __shared__ float cuml[64], nwl[64];
  const size_t base = (size_t)c * 16 + h;
  for (int e = tid; e < 2048; e += 256) {
    int r = e >> 6, d = e & 63;
    qT[d][r] = P[(size_t)(c * 32 + r) * NP + h * 64 + d];
  }
  for (int e = tid; e < 4096; e += 256) {
    int j = e >> 6, d = e & 63, s = c * 64 + j, t = s >> 1, nh = s & 1;
    kTc[d][j] = P[(size_t)t * NP + 1024 + nh * 1024 + h * 64 + d];
  }
  if (tid < 64) { cuml[tid] = cumbuf[base * 64 + tid]; nwl[tid] = nw[tid]; }
  __syncthreads();
  // ---- pass1: QK^T -> PmT ----
  {
    float pa[2][4] = {};
#pragma unroll 4
    for (int d = 0; d < 64; d++) {
      f32x2 qv = *(const f32x2*)&qT[d][2 * rb];
      f32x4 kv = *(const f32x4*)&kTc[d][4 * jb];
#pragma unroll
      for (int rr = 0; rr < 2; rr++)
#pragma unroll
        for (int cc = 0; cc < 4; cc++) pa[rr][cc] += qv[rr] * kv[cc];
    }
#pragma unroll
    for (int rr = 0; rr < 2; rr++)
#pragma unroll
      for (int cc = 0; cc < 4; cc++) {
        int r = 2 * rb + rr, i = 2 * r + 1, j = 4 * jb + cc;
        PmT[j][r] = (j <= i) ? expf(cuml[i] - cuml[j]) * pa[rr][cc] : 0.f;
      }
  }
  __syncthreads();
  // ---- stage2: kTc <- S0, Ul <- W^T ----
  for (int e = tid; e < 4096; e += 256) {
    int i = e >> 6, m = e & 63;
    kTc[m][i] = bf2f(S0Tbuf[base * 4096 + e]);
    Ul[m][i]  = bf2f(Wbuf[base * 4096 + e]);
  }
  __syncthreads();
  // ---- B2 compute: acc = W*S0 ----
  float b2acc[4][4] = {};
  {
#pragma unroll 4
    for (int m = 0; m < 64; m++) {
      f32x4 wv = *(const f32x4*)&Ul[m][4 * rb];
      f32x4 sv = *(const f32x4*)&kTc[m][4 * jb];
#pragma unroll
      for (int rr = 0; rr < 4; rr++)
#pragma unroll
        for (int cc = 0; cc < 4; cc++) b2acc[rr][cc] += wv[rr] * sv[cc];
    }
  }
  __syncthreads();   // W^T reads done before U overwrite
  // ---- U write into Ul ----
#pragma unroll
  for (int rr = 0; rr < 4; rr++) {
    int i = 4 * rb + rr;
    u16x4 uv = *(const u16x4*)&Uvbuf[base * 4096 + (size_t)i * 64 + 4 * jb];
#pragma unroll
    for (int cc = 0; cc < 4; cc++)
      Ul[i][4 * jb + cc] = bf2f(f2bf(bf2f(uv[cc]) - b2acc[rr][cc]));
  }
  __syncthreads();
  // ---- pass2 ----
  float o[2][4];
  {
    float a1[2][4] = {}, a2[2][4] = {};
#pragma unroll 4
    for (int m = 0; m < 64; m++) {
      f32x2 qv = *(const f32x2*)&qT[m][2 * rb];
      f32x4 sv = *(const f32x4*)&kTc[m][4 * jb];
#pragma unroll
      for (int rr = 0; rr < 2; rr++)
#pragma unroll
        for (int cc = 0; cc < 4; cc++) a1[rr][cc] += qv[rr] * sv[cc];
    }
    // triangular: PmT[j][r]=0 for j>2r+1; max needed j = 4rb+3
#pragma unroll 4
    for (int j = 0; j < 4 * rb + 4; j++) {
      f32x2 pv = *(const f32x2*)&PmT[j][2 * rb];
      f32x4 uv = *(const f32x4*)&Ul[j][4 * jb];
#pragma unroll
      for (int rr = 0; rr < 2; rr++)
#pragma unroll
        for (int cc = 0; cc < 4; cc++) a2[rr][cc] += pv[rr] * uv[cc];
    }
#pragma unroll
    for (int rr = 0; rr < 2; rr++) {
      float ec = expf(cuml[2 * (2 * rb + rr) + 1]);
#pragma unroll
      for (int cc = 0; cc < 4; cc++) o[rr][cc] = a1[rr][cc] * ec + a2[rr][cc];
    }
  }
  __syncthreads();
  float* ol = &qT[0][0];   // [32][68]
#pragma unroll
  for (int rr = 0; rr < 2; rr++)
#pragma unroll
    for (int cc = 0; cc < 4; cc++)
      ol[(2 * rb + rr) * 68 + 4 * jb + cc] = o[rr][cc];
  __syncthreads();
  for (int e = tid; e < 2048; e += 256) {
    int r = e >> 6, d = e & 63;
    float ov = ol[r * 68 + d];
    float ss = ov * ov;
#pragma unroll
    for (int off = 32; off; off >>= 1) ss += __shfl_xor(ss, off);
    float on = ov * rsqrtf(ss * (1.f / 64.f) + 1e-5f) * nwl[d];
    int t = c * 32 + r;
    float gt = P[(size_t)t * NP + 5168 + h * 64 + d];
    float sw = gt / (1.f + expf(-gt));
    ybuf[(size_t)t * 1024 + h * 64 + d] = f2bf(on * sw);
  }
}

extern "C" void kernel_launch(void* const* d_in, const int* in_sizes, int n_in,
                              void* d_out, int out_size, void* d_ws, size_t ws_size,
                              hipStream_t stream) {
  const float* x       = (const float*)d_in[0];
  const float* Wq      = (const float*)d_in[1];
  const float* Wk      = (const float*)d_in[2];
  const float* Wv      = (const float*)d_in[3];
  const float* Wb      = (const float*)d_in[4];
  const float* Wa      = (const float*)d_in[5];
  const float* A_log   = (const float*)d_in[6];
  const float* dt_bias = (const float*)d_in[7];
  const float* Wg      = (const float*)d_in[8];
  const float* nw      = (const float*)d_in[9];
  const float* Wo      = (const float*)d_in[10];
  float* out = (float*)d_out;

  char* w = (char*)d_ws;
  size_t used = 0;
  auto alloc = [&](size_t bytes) {
    char* p = w + used; used += (bytes + 255) & ~(size_t)255; return p;
  };
  u16*   xb    = (u16*)  alloc(2048UL * 1024 * 2);
  u16*   WT    = (u16*)  alloc(6272UL * 1024 * 2);   // padded to 49*128 rows
  u16*   WoT   = (u16*)  alloc(1024UL * 1024 * 2);
  float* P     = (float*)alloc(2048UL * NP * 4);
  float* betab = (float*)alloc(4096UL * 16 * 4);
  float* gbuf  = (float*)alloc(2048UL * 16 * 4);
  u16*   ybuf  = (u16*)  alloc(2048UL * 1024 * 2);
  u16*   Wbuf  = (u16*)  alloc((size_t)NC * 16 * 4096 * 2);
  u16*   Uvbuf = (u16*)  alloc((size_t)NC * 16 * 4096 * 2);
  u16*   S0Tb  = (u16*)  alloc((size_t)NC * 16 * 4096 * 2);
  float* Mbuf  = (float*)alloc((size_t)NC * 16 * 4096 * 4);
  float* NTbuf = (float*)alloc((size_t)NC * 16 * 4096 * 4);
  float* cumb  = (float*)alloc((size_t)NC * 16 * 64 * 4);

  auto tgrid = [](long n) { return dim3((unsigned)((n + 255) / 256)); };
  if (used > ws_size) {
    beacon_kernel<<<tgrid(out_size), 256, 0, stream>>>(out, out_size);
    return;
  }

  // zero pad rows 6192..6271 (edge tile of the 128-wide gemm reads them)
  hipMemsetAsync(WT + 6192UL * 1024, 0, 80UL * 1024 * 2, stream);

  cvt_kernel<<<tgrid(2048L*1024), 256, 0, stream>>>(x, xb, 2048L * 1024);
  transAll_kernel<<<dim3(226, 32), 256, 0, stream>>>(Wq, Wk, Wv, Wb, Wa, Wg, Wo, WT, WoT);

  // P (fp32) = xb @ [Wq|Wk|Wv|Wb|Wa|Wg]
  gemm128<<<dim3(16, 49), 256, 0, stream>>>(xb, WT, P, nullptr, 1024, 1024, NP, NP, 0);
  prep_kernel<<<dim3(2048 * 4), 256, 0, stream>>>(P, A_log, dt_bias, betab, gbuf);

  phaseA_kernel<<<dim3(NC, 16), 256, 0, stream>>>(P, betab, gbuf, Wbuf, Uvbuf, Mbuf, NTbuf, cumb);
  phaseB_kernel<<<dim3(8, 16), 128, 0, stream>>>(Mbuf, NTbuf, S0Tb);
  phaseC_kernel<<<dim3(NC, 16), 256, 0, stream>>>(P, cumb, Wbuf, Uvbuf, S0Tb, nw, ybuf);

  // out (fp32) = ybuf @ Wo
  gemm128<<<dim3(16, 8), 256, 0, stream>>>(ybuf, WoT, out, nullptr, 1024, 1024, 1024, 1024, 0);
}

// Round 11
// 400.163 us; speedup vs baseline: 1.1233x; 1.1233x over previous
//
#include <hip/hip_runtime.h>
#include <stdint.h>

// ---------------------------------------------------------------------------
// DeltaNet (gated delta rule) forward, MI355X gfx950. Round 23.
// Round 22 post-mortem: phaseB v3 (8 cols/block) = 128 blocks -> HALF the
// CUs idle + doubled per-chunk chain: +60us. REVERTED to r21 v2 (4 cols/
// block, 2 waves, LDS-shared M, 256 blocks = 1/CU). phaseB CLOSED: 4 cols/
// block is the unique minimal-traffic point with all CUs busy.
// Everything else unchanged from r21 (401us config; this session's clocks
// ~10% faster per phaseA 107 vs 119.6).
// P column map: [0,1024) q | [1024,3072) k | [3072,5120) v |
//   [5120,5152) beta-pre | [5152,5168) a-pre | [5168,6192) gate | pad
// ---------------------------------------------------------------------------

typedef unsigned short u16;
typedef __attribute__((ext_vector_type(8))) short bf16x8;
typedef __attribute__((ext_vector_type(4))) float f32x4;
typedef __attribute__((ext_vector_type(2))) float f32x2;
typedef __attribute__((ext_vector_type(4))) unsigned short u16x4;

#define TT 2048
#define NP 6208
#define NC 64
#define CS 64

__device__ __forceinline__ u16 f2bf(float f) {
  union { float f; uint32_t u; } v; v.f = f;
  uint32_t r = v.u + 0x7fffu + ((v.u >> 16) & 1u);  // RNE
  return (u16)(r >> 16);
}
__device__ __forceinline__ float bf2f(u16 b) {
  union { uint32_t u; float f; } v; v.u = ((uint32_t)b) << 16; return v.f;
}

// async global->LDS, 16B per lane; LDS dest = wave-uniform base + lane*16
__device__ __forceinline__ void gload_lds16(const u16* g, u16* l) {
  __builtin_amdgcn_global_load_lds(
      (__attribute__((address_space(1))) const void*)(uintptr_t)g,
      (__attribute__((address_space(3))) void*)(uint32_t)(uintptr_t)l, 16, 0, 0);
}

__global__ void cvt_kernel(const float* __restrict__ src, u16* __restrict__ dst, long n) {
  long i = (long)blockIdx.x * 256 + threadIdx.x;
  if (i < n) dst[i] = f2bf(src[i]);
}

// fused transpose+convert of all 7 weight matrices (rows always 1024)
__global__ __launch_bounds__(256) void transAll_kernel(
    const float* __restrict__ Wq, const float* __restrict__ Wk,
    const float* __restrict__ Wv, const float* __restrict__ Wb,
    const float* __restrict__ Wa, const float* __restrict__ Wg,
    const float* __restrict__ Wo, u16* __restrict__ WT, u16* __restrict__ WoT) {
  int bx = blockIdx.x;
  const float* src; u16* dst; int cols;
  if      (bx < 32)  { src = Wq; dst = WT;                cols = 1024; }
  else if (bx < 96)  { src = Wk; dst = WT + 1024UL*1024;  cols = 2048; bx -= 32; }
  else if (bx < 160) { src = Wv; dst = WT + 3072UL*1024;  cols = 2048; bx -= 96; }
  else if (bx < 161) { src = Wb; dst = WT + 5120UL*1024;  cols = 32;   bx -= 160; }
  else if (bx < 162) { src = Wa; dst = WT + 5152UL*1024;  cols = 16;   bx -= 161; }
  else if (bx < 194) { src = Wg; dst = WT + 5168UL*1024;  cols = 1024; bx -= 162; }
  else               { src = Wo; dst = WoT;               cols = 1024; bx -= 194; }
  __shared__ float tile[32][33];
  const int tx = threadIdx.x & 31, ty = threadIdx.x >> 5;
  const int c0 = bx * 32, r0 = blockIdx.y * 32;
  for (int rr = ty; rr < 32; rr += 8)
    if (c0 + tx < cols) tile[rr][tx] = src[(size_t)(r0 + rr) * cols + c0 + tx];
  __syncthreads();
  for (int rr = ty; rr < 32; rr += 8)
    if (c0 + rr < cols) dst[(size_t)(c0 + rr) * 1024 + r0 + tx] = f2bf(tile[tx][rr]);
}

__global__ __launch_bounds__(256) void beacon_kernel(float* __restrict__ out, int n) {
  int i = blockIdx.x * 256 + threadIdx.x;
  if (i < n) out[i] = 4000.0f;
}

// 128x128-tile GEMM: C = A[M,K](bf16,lda) * BT[N,K]^T(bf16, row stride K).
// 4 waves, each a 64x64 quadrant. BT must be zero-padded to grid.y*128 rows.
// Staging via global_load_lds (m97 structure, linear [128][32] LDS).
__global__ __launch_bounds__(256) void gemm128(const u16* __restrict__ A,
    const u16* __restrict__ BT, float* __restrict__ Cf, u16* __restrict__ Cb,
    int K, int lda, int ldc, int Nmax, int out_bf16) {
  const int bm = blockIdx.x * 128, bn = blockIdx.y * 128;
  const int tid = threadIdx.x, w = tid >> 6, lane = tid & 63;
  const int wr = (w >> 1) * 64, wc = (w & 1) * 64;
  const int quad = lane >> 4, r = lane & 15;
  __shared__ u16 As[128][32], Bs[128][32];   // linear: global_load_lds dest
  f32x4 acc[4][4] = {};
  // wave w stages rows w*32..w*32+31 (two 16-row instructions)
  const int sr = w * 32 + (lane >> 2);       // global row for inst 0
  const int sc = (lane & 3) * 8;             // u16 col offset within 32-wide tile
  const u16* gA0 = A  + (size_t)(bm + sr) * lda + sc;
  const u16* gA1 = A  + (size_t)(bm + sr + 16) * lda + sc;
  const u16* gB0 = BT + (size_t)(bn + sr) * K + sc;
  const u16* gB1 = BT + (size_t)(bn + sr + 16) * K + sc;
  u16* lA0 = &As[w * 32][0];
  u16* lA1 = &As[w * 32 + 16][0];
  u16* lB0 = &Bs[w * 32][0];
  u16* lB1 = &Bs[w * 32 + 16][0];
  for (int ks = 0; ks < K; ks += 32) {
    __syncthreads();   // prev-iter readers done before LDS overwrite
    gload_lds16(gA0 + ks, lA0);
    gload_lds16(gA1 + ks, lA1);
    gload_lds16(gB0 + ks, lB0);
    gload_lds16(gB1 + ks, lB1);
    __syncthreads();   // compiler drains vmcnt(0) before barrier
    bf16x8 af[4], bf[4];
#pragma unroll
    for (int i = 0; i < 4; i++) af[i] = *(const bf16x8*)&As[wr + i * 16 + r][quad * 8];
#pragma unroll
    for (int j = 0; j < 4; j++) bf[j] = *(const bf16x8*)&Bs[wc + j * 16 + r][quad * 8];
#pragma unroll
    for (int i = 0; i < 4; i++)
#pragma unroll
      for (int j = 0; j < 4; j++)
        acc[i][j] = __builtin_amdgcn_mfma_f32_16x16x32_bf16(af[i], bf[j], acc[i][j], 0, 0, 0);
  }
#pragma unroll
  for (int i = 0; i < 4; i++)
#pragma unroll
    for (int j = 0; j < 4; j++)
#pragma unroll
      for (int rg = 0; rg < 4; rg++) {
        int row = bm + wr + i * 16 + quad * 4 + rg;
        int col = bn + wc + j * 16 + r;
        if (col < Nmax) {
          float v = acc[i][j][rg];
          if (out_bf16) Cb[(size_t)row * ldc + col] = f2bf(v);
          else          Cf[(size_t)row * ldc + col] = v;
        }
      }
}

// 4 heads per block (one per wave); per-wave code identical to the old
// 64-thread block version (launch-overhead reduction only).
__global__ __launch_bounds__(256) void prep_kernel(float* __restrict__ P,
    const float* __restrict__ A_log, const float* __restrict__ dt_bias,
    float* __restrict__ betab, float* __restrict__ gbuf) {
  const int t = blockIdx.x >> 2, w = threadIdx.x >> 6, lane = threadIdx.x & 63;
  const int h = (blockIdx.x & 3) * 4 + w;
  float* Pt = P + (size_t)t * NP;
  float qv = Pt[h * 64 + lane];
  float ss = qv * qv;
#pragma unroll
  for (int off = 32; off; off >>= 1) ss += __shfl_xor(ss, off);
  Pt[h * 64 + lane] = qv * rsqrtf(ss + 1e-6f) * 0.125f;
#pragma unroll
  for (int nh = 0; nh < 2; nh++) {
    float kv = Pt[1024 + nh * 1024 + h * 64 + lane];
    float ks = kv * kv;
#pragma unroll
    for (int off = 32; off; off >>= 1) ks += __shfl_xor(ks, off);
    Pt[1024 + nh * 1024 + h * 64 + lane] = kv * rsqrtf(ks + 1e-6f);
  }
  if (lane < 2) {
    float bb = Pt[5120 + lane * 16 + h];
    betab[(size_t)(2 * t + lane) * 16 + h] = 2.f / (1.f + expf(-bb));
  }
  if (lane == 0) {
    float a = Pt[5152 + h] + dt_bias[h];
    float sp = (a > 20.f) ? a : log1pf(expf(a));
    gbuf[t * 16 + h] = -expf(A_log[h]) * sp;
  }
}

// phase A: per (c,h): G, T, W(bf16), M(fp32), Uv(bf16), NT(fp32), cum.
// 3 LDS arrays (53248 B -> 3 blocks/CU): LA: kT->Tt->Uv, LB: kf, LC: Sc->v->W.
// (r13 version verbatim; all MFMA/fusion/reg-carry variants measured worse)
__global__ __launch_bounds__(256, 1) void phaseA_kernel(const float* __restrict__ P,
    const float* __restrict__ betab, const float* __restrict__ gbuf,
    u16* __restrict__ Wbuf, u16* __restrict__ Uvbuf,
    float* __restrict__ Mbuf, float* __restrict__ NTbuf, float* __restrict__ cumbuf) {
  const int c = blockIdx.x, h = blockIdx.y, tid = threadIdx.x;
  const int bi = tid >> 4, bj = tid & 15;
  __shared__ float LA[64][68];   // kT -> Tt -> Uv
  __shared__ float LB[64][68];   // kf (persistent)
  __shared__ float LC[64][68];   // Sc -> v -> W
  __shared__ float cumch[64], betach[64], bbch[64], rowfl[64];
  const size_t base = ((size_t)c * 16 + h) * 4096;

  for (int e = tid; e < 4096; e += 256) {
    int i = e >> 6, d = e & 63, s = c * 64 + i, t = s >> 1, nh = s & 1;
    float kv = P[(size_t)t * NP + 1024 + nh * 1024 + h * 64 + d];
    LB[i][d] = kv; LA[d][i] = kv;
  }
  if (tid < 64) betach[tid] = betab[(size_t)(c * 64 + tid) * 16 + h];
  __syncthreads();
  if (tid == 0) {
    float cum = 0.f;
    for (int i = 0; i < 64; i++) {
      if ((i & 1) == 0) cum += gbuf[(c * 32 + (i >> 1)) * 16 + h];
      cumch[i] = cum;
    }
  }
  __syncthreads();
  if (tid < 64) {
    bbch[tid] = betach[tid] * expf(cumch[tid]);
    rowfl[tid] = expf(cumch[63] - cumch[tid]);
  }
  // G then scale -> LC
  {
    float acc[4][4] = {};
#pragma unroll 4
    for (int d = 0; d < 64; d++) {
      f32x4 a = *(const f32x4*)&LA[d][4 * bi];
      f32x4 b = *(const f32x4*)&LA[d][4 * bj];
#pragma unroll
      for (int rr = 0; rr < 4; rr++)
#pragma unroll
        for (int cc = 0; cc < 4; cc++) acc[rr][cc] += a[rr] * b[cc];
    }
#pragma unroll
    for (int rr = 0; rr < 4; rr++)
#pragma unroll
      for (int cc = 0; cc < 4; cc++) {
        int i = 4 * bi + rr, j = 4 * bj + cc;
        LC[i][j] = (j < i) ? betach[i] * expf(cumch[i] - cumch[j]) * acc[rr][cc] : 0.f;
      }
  }
  __syncthreads();
  // T = (I+A)^-1 forward substitution: LC(Sc) -> LA[j][i] (Tt)
  {
    int col = tid >> 2, part = tid & 3;
    if (part == 0) LA[col][0] = (col == 0) ? 1.f : 0.f;
    for (int i = 1; i < 64; i++) {
      float partial = 0.f;
      for (int j = col + part; j < i; j += 4) partial += LC[i][j] * LA[col][j];
      partial += __shfl_xor(partial, 1);
      partial += __shfl_xor(partial, 2);
      if (part == 0) LA[col][i] = ((i == col) ? 1.f : 0.f) - partial;
    }
  }
  __syncthreads();
  // prefetch v into regs now; ds_write after M (latency hides under W+M)
  float vreg[16];
  {
    const int vi = tid >> 6, vd = tid & 63;
#pragma unroll
    for (int s = 0; s < 16; s++) {
      int i = vi + 4 * s, ss = c * 64 + i, t = ss >> 1, nh = ss & 1;
      vreg[s] = P[(size_t)t * NP + 3072 + nh * 1024 + h * 64 + vd];
    }
  }
  // W[i][d] = sum_{j<=i} T[i][j]*bb[j]*k[j][d]  (triangular trip)
  {
    float acc[4][4] = {};
#pragma unroll 4
    for (int j = 0; j < 4 * bi + 4; j++) {
      f32x4 tv = *(const f32x4*)&LA[j][4 * bi];
      f32x4 kv = *(const f32x4*)&LB[j][4 * bj];
      float bbj = bbch[j];
#pragma unroll
      for (int rr = 0; rr < 4; rr++)
#pragma unroll
        for (int cc = 0; cc < 4; cc++) acc[rr][cc] += tv[rr] * bbj * kv[cc];
    }
#pragma unroll
    for (int rr = 0; rr < 4; rr++) {
      int i = 4 * bi + rr;
      u16x4 wb;
#pragma unroll
      for (int cc = 0; cc < 4; cc++) { LC[i][4 * bj + cc] = acc[rr][cc]; wb[cc] = f2bf(acc[rr][cc]); }
      *(u16x4*)&Wbuf[base + (size_t)i * 64 + 4 * bj] = wb;
    }
  }
  __syncthreads();
  // M[m][mm] = bL*delta - sum_i rowf[i]*k[i][m]*W[i][mm]
  {
    const float bL = expf(cumch[63]);
    float acc[4][4] = {};
#pragma unroll 4
    for (int i = 0; i < 64; i++) {
      f32x4 kv = *(const f32x4*)&LB[i][4 * bi];
      f32x4 wv = *(const f32x4*)&LC[i][4 * bj];
      float rf = rowfl[i];
#pragma unroll
      for (int rr = 0; rr < 4; rr++)
#pragma unroll
        for (int cc = 0; cc < 4; cc++) acc[rr][cc] += rf * kv[rr] * wv[cc];
    }
#pragma unroll
    for (int rr = 0; rr < 4; rr++) {
      int m = 4 * bi + rr;
      f32x4 mv;
#pragma unroll
      for (int cc = 0; cc < 4; cc++)
        mv[cc] = ((m == 4 * bj + cc) ? bL : 0.f) - acc[rr][cc];
      *(f32x4*)&Mbuf[base + (size_t)m * 64 + 4 * bj] = mv;
    }
  }
  __syncthreads();
  // stage v (from regs) over LC
  {
    const int vi = tid >> 6, vd = tid & 63;
#pragma unroll
    for (int s = 0; s < 16; s++) LC[vi + 4 * s][vd] = vreg[s];
  }
  __syncthreads();
  // Uv[i][d] = sum_{j<=i} T[i][j]*beta[j]*v[j][d] -> regs (LA still = Tt)
  float ua[4][4] = {};
  {
#pragma unroll 4
    for (int j = 0; j < 4 * bi + 4; j++) {
      f32x4 tv = *(const f32x4*)&LA[j][4 * bi];
      f32x4 vv = *(const f32x4*)&LC[j][4 * bj];
      float be = betach[j];
#pragma unroll
      for (int rr = 0; rr < 4; rr++)
#pragma unroll
        for (int cc = 0; cc < 4; cc++) ua[rr][cc] += tv[rr] * be * vv[cc];
    }
  }
  __syncthreads();   // all Tt reads complete before overwrite
  {
#pragma unroll
    for (int rr = 0; rr < 4; rr++) {
      int i = 4 * bi + rr;
      u16x4 ub;
#pragma unroll
      for (int cc = 0; cc < 4; cc++) { LA[i][4 * bj + cc] = ua[rr][cc]; ub[cc] = f2bf(ua[rr][cc]); }
      *(u16x4*)&Uvbuf[base + (size_t)i * 64 + 4 * bj] = ub;
    }
  }
  __syncthreads();
  // NT[d][m] = sum_i rowf[i]*k[i][m]*Uv[i][d]
  {
    float acc[4][4] = {};
#pragma unroll 4
    for (int i = 0; i < 64; i++) {
      f32x4 kv = *(const f32x4*)&LB[i][4 * bi];
      f32x4 uv = *(const f32x4*)&LA[i][4 * bj];
      float rf = rowfl[i];
#pragma unroll
      for (int rr = 0; rr < 4; rr++)
#pragma unroll
        for (int cc = 0; cc < 4; cc++) acc[rr][cc] += rf * kv[rr] * uv[cc];
    }
#pragma unroll
    for (int cc = 0; cc < 4; cc++) {
      f32x4 nv;
#pragma unroll
      for (int rr = 0; rr < 4; rr++) nv[rr] = acc[rr][cc];
      *(f32x4*)&NTbuf[base + (size_t)(4 * bj + cc) * 64 + 4 * bi] = nv;
    }
  }
  if (tid < 64) cumbuf[((size_t)c * 16 + h) * 64 + tid] = cumch[tid];
}

// phase B v2 (r21): 4 cols/block, 2 waves; M chunk staged once into LDS
// (dbuf, pad-68) and shared by both waves -> 256 blocks (1/CU), 256MB M
// traffic. Per-column math/order identical to r13 (bit-exact).
__global__ __launch_bounds__(128) void phaseB_kernel(const float* __restrict__ Mbuf,
    const float* __restrict__ NTbuf, u16* __restrict__ S0Tbuf) {
  const int g = blockIdx.x, h = blockIdx.y;
  const int tid = threadIdx.x, wv = tid >> 6, l = tid & 63;
  const int c0 = 4 * g + 2 * wv, c1 = c0 + 1;
  __shared__ float Ms[2][64][68];
  __shared__ float Ssh[2][4][64];
  float s0 = 0.f, s1 = 0.f;
  float n0, n1;
  f32x4 mn[8];
  // stage chunk 0: thread t covers f32x4-slots t*8..t*8+7 (row=slot>>4, s=slot&15)
  {
    const float* Mc = Mbuf + (size_t)h * 4096;
#pragma unroll
    for (int i = 0; i < 8; i++) {
      int sl = tid * 8 + i;
      mn[i] = *(const f32x4*)(Mc + (sl >> 4) * 64 + (sl & 15) * 4);
    }
#pragma unroll
    for (int i = 0; i < 8; i++) {
      int sl = tid * 8 + i;
      *(f32x4*)&Ms[0][sl >> 4][(sl & 15) * 4] = mn[i];
    }
    const float* Nc = NTbuf + (size_t)h * 4096;
    n0 = Nc[c0 * 64 + l]; n1 = Nc[c1 * 64 + l];
  }
  Ssh[0][2 * wv][l] = 0.f; Ssh[0][2 * wv + 1][l] = 0.f;
  __syncthreads();
  int p = 0;
  for (int c = 0; c < NC; c++) {
    const size_t base = ((size_t)c * 16 + h) * 4096;
    S0Tbuf[base + (size_t)c0 * 64 + l] = f2bf(s0);
    S0Tbuf[base + (size_t)c1 * 64 + l] = f2bf(s1);
    float nn0 = 0.f, nn1 = 0.f;
    if (c + 1 < NC) {
      // issue next-chunk M loads (latency hides under compute below)
      const float* Mn = Mbuf + ((size_t)(c + 1) * 16 + h) * 4096;
#pragma unroll
      for (int i = 0; i < 8; i++) {
        int sl = tid * 8 + i;
        mn[i] = *(const f32x4*)(Mn + (sl >> 4) * 64 + (sl & 15) * 4);
      }
      const float* Nn = NTbuf + ((size_t)(c + 1) * 16 + h) * 4096;
      nn0 = Nn[c0 * 64 + l]; nn1 = Nn[c1 * 64 + l];
    }
    float acc0 = n0, acc1 = n1;
#pragma unroll
    for (int q = 0; q < 16; q++) {
      f32x4 mv = *(const f32x4*)&Ms[p][l][4 * q];
      f32x4 sv0 = *(const f32x4*)&Ssh[p][2 * wv][4 * q];
      f32x4 sv1 = *(const f32x4*)&Ssh[p][2 * wv + 1][4 * q];
#pragma unroll
      for (int t = 0; t < 4; t++) { acc0 += mv[t] * sv0[t]; acc1 += mv[t] * sv1[t]; }
    }
    s0 = acc0; s1 = acc1;
    Ssh[p ^ 1][2 * wv][l] = s0; Ssh[p ^ 1][2 * wv + 1][l] = s1;
    if (c + 1 < NC) {
#pragma unroll
      for (int i = 0; i < 8; i++) {
        int sl = tid * 8 + i;
        *(f32x4*)&Ms[p ^ 1][sl >> 4][(sl & 15) * 4] = mn[i];
      }
    }
    __syncthreads();
    p ^= 1;
    n0 = nn0; n1 = nn1;
  }
}

// phase C (with phaseB2 fused in):
//   kTc: k -> S0 ; Ul: W^T -> U (U = Uv - W*S0). pass2 byte-identical.
__global__ __launch_bounds__(256) void phaseC_kernel(const float* __restrict__ P,
    const float* __restrict__ cumbuf, const u16* __restrict__ Wbuf,
    const u16* __restrict__ Uvbuf, const u16* __restrict__ S0Tbuf,
    const float* __restrict__ nw, u16* __restrict__ ybuf) {
  const int c = blockIdx.x, h = blockIdx.y, tid = threadIdx.x;
  const int rb = tid >> 4, jb = tid & 15;
  __shared__ float qT[64][36];    // [d][r]; reused as ol[32][68]
  __shared__ float kTc[64][68];   // k[d][j] -> S0l[m][d]
  __shared__ float Ul[64][68];    // WTl[m][i] -> U[j][d]
  __shared__ float PmT[64][36];
  __shared__ float cuml[64], nwl[64];
  const size_t base = (size_t)c * 16 + h;
  for (int e = tid; e < 2048; e += 256) {
    int r = e >> 6, d = e & 63;
    qT[d][r] = P[(size_t)(c * 32 + r) * NP + h * 64 + d];
  }
  for (int e = tid; e < 4096; e += 256) {
    int j = e >> 6, d = e & 63, s = c * 64 + j, t = s >> 1, nh = s & 1;
    kTc[d][j] = P[(size_t)t * NP + 1024 + nh * 1024 + h * 64 + d];
  }
  if (tid < 64) { cuml[tid] = cumbuf[base * 64 + tid]; nwl[tid] = nw[tid]; }
  __syncthreads();
  // ---- pass1: QK^T -> PmT ----
  {
    float pa[2][4] = {};
#pragma unroll 4
    for (int d = 0; d < 64; d++) {
      f32x2 qv = *(const f32x2*)&qT[d][2 * rb];
      f32x4 kv = *(const f32x4*)&kTc[d][4 * jb];
#pragma unroll
      for (int rr = 0; rr < 2; rr++)
#pragma unroll
        for (int cc = 0; cc < 4; cc++) pa[rr][cc] += qv[rr] * kv[cc];
    }
#pragma unroll
    for (int rr = 0; rr < 2; rr++)
#pragma unroll
      for (int cc = 0; cc < 4; cc++) {
        int r = 2 * rb + rr, i = 2 * r + 1, j = 4 * jb + cc;
        PmT[j][r] = (j <= i) ? expf(cuml[i] - cuml[j]) * pa[rr][cc] : 0.f;
      }
  }
  __syncthreads();
  // ---- stage2: kTc <- S0, Ul <- W^T ----
  for (int e = tid; e < 4096; e += 256) {
    int i = e >> 6, m = e & 63;
    kTc[m][i] = bf2f(S0Tbuf[base * 4096 + e]);
    Ul[m][i]  = bf2f(Wbuf[base * 4096 + e]);
  }
  __syncthreads();
  // ---- B2 compute: acc = W*S0 ----
  float b2acc[4][4] = {};
  {
#pragma unroll 4
    for (int m = 0; m < 64; m++) {
      f32x4 wv = *(const f32x4*)&Ul[m][4 * rb];
      f32x4 sv = *(const f32x4*)&kTc[m][4 * jb];
#pragma unroll
      for (int rr = 0; rr < 4; rr++)
#pragma unroll
        for (int cc = 0; cc < 4; cc++) b2acc[rr][cc] += wv[rr] * sv[cc];
    }
  }
  __syncthreads();   // W^T reads done before U overwrite
  // ---- U write into Ul ----
#pragma unroll
  for (int rr = 0; rr < 4; rr++) {
    int i = 4 * rb + rr;
    u16x4 uv = *(const u16x4*)&Uvbuf[base * 4096 + (size_t)i * 64 + 4 * jb];
#pragma unroll
    for (int cc = 0; cc < 4; cc++)
      Ul[i][4 * jb + cc] = bf2f(f2bf(bf2f(uv[cc]) - b2acc[rr][cc]));
  }
  __syncthreads();
  // ---- pass2 ----
  float o[2][4];
  {
    float a1[2][4] = {}, a2[2][4] = {};
#pragma unroll 4
    for (int m = 0; m < 64; m++) {
      f32x2 qv = *(const f32x2*)&qT[m][2 * rb];
      f32x4 sv = *(const f32x4*)&kTc[m][4 * jb];
#pragma unroll
      for (int rr = 0; rr < 2; rr++)
#pragma unroll
        for (int cc = 0; cc < 4; cc++) a1[rr][cc] += qv[rr] * sv[cc];
    }
    // triangular: PmT[j][r]=0 for j>2r+1; max needed j = 4rb+3
#pragma unroll 4
    for (int j = 0; j < 4 * rb + 4; j++) {
      f32x2 pv = *(const f32x2*)&PmT[j][2 * rb];
      f32x4 uv = *(const f32x4*)&Ul[j][4 * jb];
#pragma unroll
      for (int rr = 0; rr < 2; rr++)
#pragma unroll
        for (int cc = 0; cc < 4; cc++) a2[rr][cc] += pv[rr] * uv[cc];
    }
#pragma unroll
    for (int rr = 0; rr < 2; rr++) {
      float ec = expf(cuml[2 * (2 * rb + rr) + 1]);
#pragma unroll
      for (int cc = 0; cc < 4; cc++) o[rr][cc] = a1[rr][cc] * ec + a2[rr][cc];
    }
  }
  __syncthreads();
  float* ol = &qT[0][0];   // [32][68]
#pragma unroll
  for (int rr = 0; rr < 2; rr++)
#pragma unroll
    for (int cc = 0; cc < 4; cc++)
      ol[(2 * rb + rr) * 68 + 4 * jb + cc] = o[rr][cc];
  __syncthreads();
  for (int e = tid; e < 2048; e += 256) {
    int r = e >> 6, d = e & 63;
    float ov = ol[r * 68 + d];
    float ss = ov * ov;
#pragma unroll
    for (int off = 32; off; off >>= 1) ss += __shfl_xor(ss, off);
    float on = ov * rsqrtf(ss * (1.f / 64.f) + 1e-5f) * nwl[d];
    int t = c * 32 + r;
    float gt = P[(size_t)t * NP + 5168 + h * 64 + d];
    float sw = gt / (1.f + expf(-gt));
    ybuf[(size_t)t * 1024 + h * 64 + d] = f2bf(on * sw);
  }
}

extern "C" void kernel_launch(void* const* d_in, const int* in_sizes, int n_in,
                              void* d_out, int out_size, void* d_ws, size_t ws_size,
                              hipStream_t stream) {
  const float* x       = (const float*)d_in[0];
  const float* Wq      = (const float*)d_in[1];
  const float* Wk      = (const float*)d_in[2];
  const float* Wv      = (const float*)d_in[3];
  const float* Wb      = (const float*)d_in[4];
  const float* Wa      = (const float*)d_in[5];
  const float* A_log   = (const float*)d_in[6];
  const float* dt_bias = (const float*)d_in[7];
  const float* Wg      = (const float*)d_in[8];
  const float* nw      = (const float*)d_in[9];
  const float* Wo      = (const float*)d_in[10];
  float* out = (float*)d_out;

  char* w = (char*)d_ws;
  size_t used = 0;
  auto alloc = [&](size_t bytes) {
    char* p = w + used; used += (bytes + 255) & ~(size_t)255; return p;
  };
  u16*   xb    = (u16*)  alloc(2048UL * 1024 * 2);
  u16*   WT    = (u16*)  alloc(6272UL * 1024 * 2);   // padded to 49*128 rows
  u16*   WoT   = (u16*)  alloc(1024UL * 1024 * 2);
  float* P     = (float*)alloc(2048UL * NP * 4);
  float* betab = (float*)alloc(4096UL * 16 * 4);
  float* gbuf  = (float*)alloc(2048UL * 16 * 4);
  u16*   ybuf  = (u16*)  alloc(2048UL * 1024 * 2);
  u16*   Wbuf  = (u16*)  alloc((size_t)NC * 16 * 4096 * 2);
  u16*   Uvbuf = (u16*)  alloc((size_t)NC * 16 * 4096 * 2);
  u16*   S0Tb  = (u16*)  alloc((size_t)NC * 16 * 4096 * 2);
  float* Mbuf  = (float*)alloc((size_t)NC * 16 * 4096 * 4);
  float* NTbuf = (float*)alloc((size_t)NC * 16 * 4096 * 4);
  float* cumb  = (float*)alloc((size_t)NC * 16 * 64 * 4);

  auto tgrid = [](long n) { return dim3((unsigned)((n + 255) / 256)); };
  if (used > ws_size) {
    beacon_kernel<<<tgrid(out_size), 256, 0, stream>>>(out, out_size);
    return;
  }

  // zero pad rows 6192..6271 (edge tile of the 128-wide gemm reads them)
  hipMemsetAsync(WT + 6192UL * 1024, 0, 80UL * 1024 * 2, stream);

  cvt_kernel<<<tgrid(2048L*1024), 256, 0, stream>>>(x, xb, 2048L * 1024);
  transAll_kernel<<<dim3(226, 32), 256, 0, stream>>>(Wq, Wk, Wv, Wb, Wa, Wg, Wo, WT, WoT);

  // P (fp32) = xb @ [Wq|Wk|Wv|Wb|Wa|Wg]
  gemm128<<<dim3(16, 49), 256, 0, stream>>>(xb, WT, P, nullptr, 1024, 1024, NP, NP, 0);
  prep_kernel<<<dim3(2048 * 4), 256, 0, stream>>>(P, A_log, dt_bias, betab, gbuf);

  phaseA_kernel<<<dim3(NC, 16), 256, 0, stream>>>(P, betab, gbuf, Wbuf, Uvbuf, Mbuf, NTbuf, cumb);
  phaseB_kernel<<<dim3(16, 16), 128, 0, stream>>>(Mbuf, NTbuf, S0Tb);
  phaseC_kernel<<<dim3(NC, 16), 256, 0, stream>>>(P, cumb, Wbuf, Uvbuf, S0Tb, nw, ybuf);

  // out (fp32) = ybuf @ Wo
  gemm128<<<dim3(16, 8), 256, 0, stream>>>(ybuf, WoT, out, nullptr, 1024, 1024, 1024, 1024, 0);
}

// Round 12
// 383.498 us; speedup vs baseline: 1.1721x; 1.0435x over previous
//
#include <hip/hip_runtime.h>
#include <stdint.h>

// ---------------------------------------------------------------------------
// DeltaNet (gated delta rule) forward, MI355X gfx950. Round 24.
// Round 23: 400us (r21 config restored). This round, two bit-exact edits:
//  1) q/k L2-norm fused into gemm1 epilogue (head = one wave quadrant's 64
//     cols). Butterfly replicated exactly: reg pairs (j^2, j^1) then
//     shfl_xor 8,4,2,1; scale order (v*rsqrt)*0.125 preserved. prep shrinks
//     to beta/g only (128 blocks). Saves ~50MB P round-trip.
//  2) gemm2 -> gemm64 (64x128 tile, 2 waves): grid (32,8)=256 blocks = 1/CU
//     (was 128 blocks = half GPU idle). Same per-output K-chain.
// absmax must stay exactly 0.04296875 (canary for the norm-tree).
// P column map: [0,1024) q | [1024,3072) k | [3072,5120) v |
//   [5120,5152) beta-pre | [5152,5168) a-pre | [5168,6192) gate | pad
// ---------------------------------------------------------------------------

typedef unsigned short u16;
typedef __attribute__((ext_vector_type(8))) short bf16x8;
typedef __attribute__((ext_vector_type(4))) float f32x4;
typedef __attribute__((ext_vector_type(2))) float f32x2;
typedef __attribute__((ext_vector_type(4))) unsigned short u16x4;

#define TT 2048
#define NP 6208
#define NC 64
#define CS 64

__device__ __forceinline__ u16 f2bf(float f) {
  union { float f; uint32_t u; } v; v.f = f;
  uint32_t r = v.u + 0x7fffu + ((v.u >> 16) & 1u);  // RNE
  return (u16)(r >> 16);
}
__device__ __forceinline__ float bf2f(u16 b) {
  union { uint32_t u; float f; } v; v.u = ((uint32_t)b) << 16; return v.f;
}

// async global->LDS, 16B per lane; LDS dest = wave-uniform base + lane*16
__device__ __forceinline__ void gload_lds16(const u16* g, u16* l) {
  __builtin_amdgcn_global_load_lds(
      (__attribute__((address_space(1))) const void*)(uintptr_t)g,
      (__attribute__((address_space(3))) void*)(uint32_t)(uintptr_t)l, 16, 0, 0);
}

__global__ void cvt_kernel(const float* __restrict__ src, u16* __restrict__ dst, long n) {
  long i = (long)blockIdx.x * 256 + threadIdx.x;
  if (i < n) dst[i] = f2bf(src[i]);
}

// fused transpose+convert of all 7 weight matrices (rows always 1024)
__global__ __launch_bounds__(256) void transAll_kernel(
    const float* __restrict__ Wq, const float* __restrict__ Wk,
    const float* __restrict__ Wv, const float* __restrict__ Wb,
    const float* __restrict__ Wa, const float* __restrict__ Wg,
    const float* __restrict__ Wo, u16* __restrict__ WT, u16* __restrict__ WoT) {
  int bx = blockIdx.x;
  const float* src; u16* dst; int cols;
  if      (bx < 32)  { src = Wq; dst = WT;                cols = 1024; }
  else if (bx < 96)  { src = Wk; dst = WT + 1024UL*1024;  cols = 2048; bx -= 32; }
  else if (bx < 160) { src = Wv; dst = WT + 3072UL*1024;  cols = 2048; bx -= 96; }
  else if (bx < 161) { src = Wb; dst = WT + 5120UL*1024;  cols = 32;   bx -= 160; }
  else if (bx < 162) { src = Wa; dst = WT + 5152UL*1024;  cols = 16;   bx -= 161; }
  else if (bx < 194) { src = Wg; dst = WT + 5168UL*1024;  cols = 1024; bx -= 162; }
  else               { src = Wo; dst = WoT;               cols = 1024; bx -= 194; }
  __shared__ float tile[32][33];
  const int tx = threadIdx.x & 31, ty = threadIdx.x >> 5;
  const int c0 = bx * 32, r0 = blockIdx.y * 32;
  for (int rr = ty; rr < 32; rr += 8)
    if (c0 + tx < cols) tile[rr][tx] = src[(size_t)(r0 + rr) * cols + c0 + tx];
  __syncthreads();
  for (int rr = ty; rr < 32; rr += 8)
    if (c0 + rr < cols) dst[(size_t)(c0 + rr) * 1024 + r0 + tx] = f2bf(tile[tx][rr]);
}

__global__ __launch_bounds__(256) void beacon_kernel(float* __restrict__ out, int n) {
  int i = blockIdx.x * 256 + threadIdx.x;
  if (i < n) out[i] = 4000.0f;
}

// 128x128-tile GEMM: C = A[M,K](bf16,lda) * BT[N,K]^T(bf16, row stride K).
// 4 waves, each a 64x64 quadrant. BT must be zero-padded to grid.y*128 rows.
// do_norm: L2-normalize each 64-col head row in the epilogue (q tiles by<8
// scale 0.125; k tiles 8<=by<24 scale 1). Butterfly tree == prep's exactly.
__global__ __launch_bounds__(256) void gemm128(const u16* __restrict__ A,
    const u16* __restrict__ BT, float* __restrict__ Cf, u16* __restrict__ Cb,
    int K, int lda, int ldc, int Nmax, int out_bf16, int do_norm) {
  const int bm = blockIdx.x * 128, bn = blockIdx.y * 128;
  const int tid = threadIdx.x, w = tid >> 6, lane = tid & 63;
  const int wr = (w >> 1) * 64, wc = (w & 1) * 64;
  const int quad = lane >> 4, r = lane & 15;
  __shared__ u16 As[128][32], Bs[128][32];   // linear: global_load_lds dest
  f32x4 acc[4][4] = {};
  // wave w stages rows w*32..w*32+31 (two 16-row instructions)
  const int sr = w * 32 + (lane >> 2);       // global row for inst 0
  const int sc = (lane & 3) * 8;             // u16 col offset within 32-wide tile
  const u16* gA0 = A  + (size_t)(bm + sr) * lda + sc;
  const u16* gA1 = A  + (size_t)(bm + sr + 16) * lda + sc;
  const u16* gB0 = BT + (size_t)(bn + sr) * K + sc;
  const u16* gB1 = BT + (size_t)(bn + sr + 16) * K + sc;
  u16* lA0 = &As[w * 32][0];
  u16* lA1 = &As[w * 32 + 16][0];
  u16* lB0 = &Bs[w * 32][0];
  u16* lB1 = &Bs[w * 32 + 16][0];
  for (int ks = 0; ks < K; ks += 32) {
    __syncthreads();   // prev-iter readers done before LDS overwrite
    gload_lds16(gA0 + ks, lA0);
    gload_lds16(gA1 + ks, lA1);
    gload_lds16(gB0 + ks, lB0);
    gload_lds16(gB1 + ks, lB1);
    __syncthreads();   // compiler drains vmcnt(0) before barrier
    bf16x8 af[4], bf[4];
#pragma unroll
    for (int i = 0; i < 4; i++) af[i] = *(const bf16x8*)&As[wr + i * 16 + r][quad * 8];
#pragma unroll
    for (int j = 0; j < 4; j++) bf[j] = *(const bf16x8*)&Bs[wc + j * 16 + r][quad * 8];
#pragma unroll
    for (int i = 0; i < 4; i++)
#pragma unroll
      for (int j = 0; j < 4; j++)
        acc[i][j] = __builtin_amdgcn_mfma_f32_16x16x32_bf16(af[i], bf[j], acc[i][j], 0, 0, 0);
  }
  // fused L2-norm: wave quadrant = one 64-col head; per row d = j*16 + r.
  // prep's butterfly (off 32,16,8,4,2,1 on d) == reg pairs (j^2 then j^1)
  // then shfl_xor 8,4,2,1 (all within the 16-lane quad group = one row).
  int mode = 0;
  if (do_norm) { if (blockIdx.y < 8) mode = 1; else if (blockIdx.y < 24) mode = 2; }
  if (mode) {
#pragma unroll
    for (int i = 0; i < 4; i++)
#pragma unroll
      for (int rg = 0; rg < 4; rg++) {
        float a0 = acc[i][0][rg], a1 = acc[i][1][rg];
        float a2 = acc[i][2][rg], a3 = acc[i][3][rg];
        float ss = (a0 * a0 + a2 * a2) + (a1 * a1 + a3 * a3);
        ss += __shfl_xor(ss, 8);
        ss += __shfl_xor(ss, 4);
        ss += __shfl_xor(ss, 2);
        ss += __shfl_xor(ss, 1);
        float rs = rsqrtf(ss + 1e-6f);
#pragma unroll
        for (int j = 0; j < 4; j++) {
          float ov = acc[i][j][rg] * rs;
          if (mode == 1) ov *= 0.125f;
          acc[i][j][rg] = ov;
        }
      }
  }
#pragma unroll
  for (int i = 0; i < 4; i++)
#pragma unroll
    for (int j = 0; j < 4; j++)
#pragma unroll
      for (int rg = 0; rg < 4; rg++) {
        int row = bm + wr + i * 16 + quad * 4 + rg;
        int col = bn + wc + j * 16 + r;
        if (col < Nmax) {
          float v = acc[i][j][rg];
          if (out_bf16) Cb[(size_t)row * ldc + col] = f2bf(v);
          else          Cf[(size_t)row * ldc + col] = v;
        }
      }
}

// 64x128-tile GEMM for the output projection: 2 waves, 256 blocks (1/CU).
// Same per-output mfma K-chain as gemm128 (bit-exact).
__global__ __launch_bounds__(128) void gemm64(const u16* __restrict__ A,
    const u16* __restrict__ BT, float* __restrict__ C, int K, int lda, int ldc) {
  const int bm = blockIdx.x * 64, bn = blockIdx.y * 128;
  const int tid = threadIdx.x, w = tid >> 6, lane = tid & 63;
  const int wc = w * 64;
  const int quad = lane >> 4, r = lane & 15;
  __shared__ u16 As[64][32], Bs[128][32];
  f32x4 acc[4][4] = {};
  const int lr = lane >> 2;          // staging row within 16-row group
  const int sc = (lane & 3) * 8;
  for (int ks = 0; ks < K; ks += 32) {
    __syncthreads();
    if (w == 0) {
      gload_lds16(A  + (size_t)(bm +  0 + lr) * lda + ks + sc, &As[0][0]);
      gload_lds16(A  + (size_t)(bm + 16 + lr) * lda + ks + sc, &As[16][0]);
      gload_lds16(A  + (size_t)(bm + 32 + lr) * lda + ks + sc, &As[32][0]);
      gload_lds16(A  + (size_t)(bm + 48 + lr) * lda + ks + sc, &As[48][0]);
      gload_lds16(BT + (size_t)(bn +  0 + lr) * K + ks + sc, &Bs[0][0]);
      gload_lds16(BT + (size_t)(bn + 16 + lr) * K + ks + sc, &Bs[16][0]);
    } else {
      gload_lds16(BT + (size_t)(bn +  32 + lr) * K + ks + sc, &Bs[32][0]);
      gload_lds16(BT + (size_t)(bn +  48 + lr) * K + ks + sc, &Bs[48][0]);
      gload_lds16(BT + (size_t)(bn +  64 + lr) * K + ks + sc, &Bs[64][0]);
      gload_lds16(BT + (size_t)(bn +  80 + lr) * K + ks + sc, &Bs[80][0]);
      gload_lds16(BT + (size_t)(bn +  96 + lr) * K + ks + sc, &Bs[96][0]);
      gload_lds16(BT + (size_t)(bn + 112 + lr) * K + ks + sc, &Bs[112][0]);
    }
    __syncthreads();
    bf16x8 af[4], bf[4];
#pragma unroll
    for (int i = 0; i < 4; i++) af[i] = *(const bf16x8*)&As[i * 16 + r][quad * 8];
#pragma unroll
    for (int j = 0; j < 4; j++) bf[j] = *(const bf16x8*)&Bs[wc + j * 16 + r][quad * 8];
#pragma unroll
    for (int i = 0; i < 4; i++)
#pragma unroll
      for (int j = 0; j < 4; j++)
        acc[i][j] = __builtin_amdgcn_mfma_f32_16x16x32_bf16(af[i], bf[j], acc[i][j], 0, 0, 0);
  }
#pragma unroll
  for (int i = 0; i < 4; i++)
#pragma unroll
    for (int j = 0; j < 4; j++)
#pragma unroll
      for (int rg = 0; rg < 4; rg++)
        C[(size_t)(bm + i * 16 + quad * 4 + rg) * ldc + bn + wc + j * 16 + r] = acc[i][j][rg];
}

// beta/g only (q/k norm moved into gemm1 epilogue). One thread per (t,h).
__global__ __launch_bounds__(256) void prep_bg_kernel(const float* __restrict__ P,
    const float* __restrict__ A_log, const float* __restrict__ dt_bias,
    float* __restrict__ betab, float* __restrict__ gbuf) {
  const int idx = blockIdx.x * 256 + threadIdx.x;   // 32768 = (t,h)
  const int t = idx >> 4, h = idx & 15;
  const float* Pt = P + (size_t)t * NP;
  float b0 = Pt[5120 + h], b1 = Pt[5136 + h];
  betab[(size_t)(2 * t) * 16 + h]     = 2.f / (1.f + expf(-b0));
  betab[(size_t)(2 * t + 1) * 16 + h] = 2.f / (1.f + expf(-b1));
  float a = Pt[5152 + h] + dt_bias[h];
  float sp = (a > 20.f) ? a : log1pf(expf(a));
  gbuf[t * 16 + h] = -expf(A_log[h]) * sp;
}

// phase A: per (c,h): G, T, W(bf16), M(fp32), Uv(bf16), NT(fp32), cum.
// 3 LDS arrays (53248 B -> 3 blocks/CU): LA: kT->Tt->Uv, LB: kf, LC: Sc->v->W.
// (r13 version verbatim; all MFMA/fusion/reg-carry variants measured worse)
__global__ __launch_bounds__(256, 1) void phaseA_kernel(const float* __restrict__ P,
    const float* __restrict__ betab, const float* __restrict__ gbuf,
    u16* __restrict__ Wbuf, u16* __restrict__ Uvbuf,
    float* __restrict__ Mbuf, float* __restrict__ NTbuf, float* __restrict__ cumbuf) {
  const int c = blockIdx.x, h = blockIdx.y, tid = threadIdx.x;
  const int bi = tid >> 4, bj = tid & 15;
  __shared__ float LA[64][68];   // kT -> Tt -> Uv
  __shared__ float LB[64][68];   // kf (persistent)
  __shared__ float LC[64][68];   // Sc -> v -> W
  __shared__ float cumch[64], betach[64], bbch[64], rowfl[64];
  const size_t base = ((size_t)c * 16 + h) * 4096;

  for (int e = tid; e < 4096; e += 256) {
    int i = e >> 6, d = e & 63, s = c * 64 + i, t = s >> 1, nh = s & 1;
    float kv = P[(size_t)t * NP + 1024 + nh * 1024 + h * 64 + d];
    LB[i][d] = kv; LA[d][i] = kv;
  }
  if (tid < 64) betach[tid] = betab[(size_t)(c * 64 + tid) * 16 + h];
  __syncthreads();
  if (tid == 0) {
    float cum = 0.f;
    for (int i = 0; i < 64; i++) {
      if ((i & 1) == 0) cum += gbuf[(c * 32 + (i >> 1)) * 16 + h];
      cumch[i] = cum;
    }
  }
  __syncthreads();
  if (tid < 64) {
    bbch[tid] = betach[tid] * expf(cumch[tid]);
    rowfl[tid] = expf(cumch[63] - cumch[tid]);
  }
  // G then scale -> LC
  {
    float acc[4][4] = {};
#pragma unroll 4
    for (int d = 0; d < 64; d++) {
      f32x4 a = *(const f32x4*)&LA[d][4 * bi];
      f32x4 b = *(const f32x4*)&LA[d][4 * bj];
#pragma unroll
      for (int rr = 0; rr < 4; rr++)
#pragma unroll
        for (int cc = 0; cc < 4; cc++) acc[rr][cc] += a[rr] * b[cc];
    }
#pragma unroll
    for (int rr = 0; rr < 4; rr++)
#pragma unroll
      for (int cc = 0; cc < 4; cc++) {
        int i = 4 * bi + rr, j = 4 * bj + cc;
        LC[i][j] = (j < i) ? betach[i] * expf(cumch[i] - cumch[j]) * acc[rr][cc] : 0.f;
      }
  }
  __syncthreads();
  // T = (I+A)^-1 forward substitution: LC(Sc) -> LA[j][i] (Tt)
  {
    int col = tid >> 2, part = tid & 3;
    if (part == 0) LA[col][0] = (col == 0) ? 1.f : 0.f;
    for (int i = 1; i < 64; i++) {
      float partial = 0.f;
      for (int j = col + part; j < i; j += 4) partial += LC[i][j] * LA[col][j];
      partial += __shfl_xor(partial, 1);
      partial += __shfl_xor(partial, 2);
      if (part == 0) LA[col][i] = ((i == col) ? 1.f : 0.f) - partial;
    }
  }
  __syncthreads();
  // prefetch v into regs now; ds_write after M (latency hides under W+M)
  float vreg[16];
  {
    const int vi = tid >> 6, vd = tid & 63;
#pragma unroll
    for (int s = 0; s < 16; s++) {
      int i = vi + 4 * s, ss = c * 64 + i, t = ss >> 1, nh = ss & 1;
      vreg[s] = P[(size_t)t * NP + 3072 + nh * 1024 + h * 64 + vd];
    }
  }
  // W[i][d] = sum_{j<=i} T[i][j]*bb[j]*k[j][d]  (triangular trip)
  {
    float acc[4][4] = {};
#pragma unroll 4
    for (int j = 0; j < 4 * bi + 4; j++) {
      f32x4 tv = *(const f32x4*)&LA[j][4 * bi];
      f32x4 kv = *(const f32x4*)&LB[j][4 * bj];
      float bbj = bbch[j];
#pragma unroll
      for (int rr = 0; rr < 4; rr++)
#pragma unroll
        for (int cc = 0; cc < 4; cc++) acc[rr][cc] += tv[rr] * bbj * kv[cc];
    }
#pragma unroll
    for (int rr = 0; rr < 4; rr++) {
      int i = 4 * bi + rr;
      u16x4 wb;
#pragma unroll
      for (int cc = 0; cc < 4; cc++) { LC[i][4 * bj + cc] = acc[rr][cc]; wb[cc] = f2bf(acc[rr][cc]); }
      *(u16x4*)&Wbuf[base + (size_t)i * 64 + 4 * bj] = wb;
    }
  }
  __syncthreads();
  // M[m][mm] = bL*delta - sum_i rowf[i]*k[i][m]*W[i][mm]
  {
    const float bL = expf(cumch[63]);
    float acc[4][4] = {};
#pragma unroll 4
    for (int i = 0; i < 64; i++) {
      f32x4 kv = *(const f32x4*)&LB[i][4 * bi];
      f32x4 wv = *(const f32x4*)&LC[i][4 * bj];
      float rf = rowfl[i];
#pragma unroll
      for (int rr = 0; rr < 4; rr++)
#pragma unroll
        for (int cc = 0; cc < 4; cc++) acc[rr][cc] += rf * kv[rr] * wv[cc];
    }
#pragma unroll
    for (int rr = 0; rr < 4; rr++) {
      int m = 4 * bi + rr;
      f32x4 mv;
#pragma unroll
      for (int cc = 0; cc < 4; cc++)
        mv[cc] = ((m == 4 * bj + cc) ? bL : 0.f) - acc[rr][cc];
      *(f32x4*)&Mbuf[base + (size_t)m * 64 + 4 * bj] = mv;
    }
  }
  __syncthreads();
  // stage v (from regs) over LC
  {
    const int vi = tid >> 6, vd = tid & 63;
#pragma unroll
    for (int s = 0; s < 16; s++) LC[vi + 4 * s][vd] = vreg[s];
  }
  __syncthreads();
  // Uv[i][d] = sum_{j<=i} T[i][j]*beta[j]*v[j][d] -> regs (LA still = Tt)
  float ua[4][4] = {};
  {
#pragma unroll 4
    for (int j = 0; j < 4 * bi + 4; j++) {
      f32x4 tv = *(const f32x4*)&LA[j][4 * bi];
      f32x4 vv = *(const f32x4*)&LC[j][4 * bj];
      float be = betach[j];
#pragma unroll
      for (int rr = 0; rr < 4; rr++)
#pragma unroll
        for (int cc = 0; cc < 4; cc++) ua[rr][cc] += tv[rr] * be * vv[cc];
    }
  }
  __syncthreads();   // all Tt reads complete before overwrite
  {
#pragma unroll
    for (int rr = 0; rr < 4; rr++) {
      int i = 4 * bi + rr;
      u16x4 ub;
#pragma unroll
      for (int cc = 0; cc < 4; cc++) { LA[i][4 * bj + cc] = ua[rr][cc]; ub[cc] = f2bf(ua[rr][cc]); }
      *(u16x4*)&Uvbuf[base + (size_t)i * 64 + 4 * bj] = ub;
    }
  }
  __syncthreads();
  // NT[d][m] = sum_i rowf[i]*k[i][m]*Uv[i][d]
  {
    float acc[4][4] = {};
#pragma unroll 4
    for (int i = 0; i < 64; i++) {
      f32x4 kv = *(const f32x4*)&LB[i][4 * bi];
      f32x4 uv = *(const f32x4*)&LA[i][4 * bj];
      float rf = rowfl[i];
#pragma unroll
      for (int rr = 0; rr < 4; rr++)
#pragma unroll
        for (int cc = 0; cc < 4; cc++) acc[rr][cc] += rf * kv[rr] * uv[cc];
    }
#pragma unroll
    for (int cc = 0; cc < 4; cc++) {
      f32x4 nv;
#pragma unroll
      for (int rr = 0; rr < 4; rr++) nv[rr] = acc[rr][cc];
      *(f32x4*)&NTbuf[base + (size_t)(4 * bj + cc) * 64 + 4 * bi] = nv;
    }
  }
  if (tid < 64) cumbuf[((size_t)c * 16 + h) * 64 + tid] = cumch[tid];
}

// phase B v2 (r21): 4 cols/block, 2 waves; M chunk staged once into LDS
// (dbuf, pad-68) and shared by both waves -> 256 blocks (1/CU), 256MB M
// traffic. Per-column math/order identical to r13 (bit-exact).
__global__ __launch_bounds__(128) void phaseB_kernel(const float* __restrict__ Mbuf,
    const float* __restrict__ NTbuf, u16* __restrict__ S0Tbuf) {
  const int g = blockIdx.x, h = blockIdx.y;
  const int tid = threadIdx.x, wv = tid >> 6, l = tid & 63;
  const int c0 = 4 * g + 2 * wv, c1 = c0 + 1;
  __shared__ float Ms[2][64][68];
  __shared__ float Ssh[2][4][64];
  float s0 = 0.f, s1 = 0.f;
  float n0, n1;
  f32x4 mn[8];
  // stage chunk 0: thread t covers f32x4-slots t*8..t*8+7 (row=slot>>4, s=slot&15)
  {
    const float* Mc = Mbuf + (size_t)h * 4096;
#pragma unroll
    for (int i = 0; i < 8; i++) {
      int sl = tid * 8 + i;
      mn[i] = *(const f32x4*)(Mc + (sl >> 4) * 64 + (sl & 15) * 4);
    }
#pragma unroll
    for (int i = 0; i < 8; i++) {
      int sl = tid * 8 + i;
      *(f32x4*)&Ms[0][sl >> 4][(sl & 15) * 4] = mn[i];
    }
    const float* Nc = NTbuf + (size_t)h * 4096;
    n0 = Nc[c0 * 64 + l]; n1 = Nc[c1 * 64 + l];
  }
  Ssh[0][2 * wv][l] = 0.f; Ssh[0][2 * wv + 1][l] = 0.f;
  __syncthreads();
  int p = 0;
  for (int c = 0; c < NC; c++) {
    const size_t base = ((size_t)c * 16 + h) * 4096;
    S0Tbuf[base + (size_t)c0 * 64 + l] = f2bf(s0);
    S0Tbuf[base + (size_t)c1 * 64 + l] = f2bf(s1);
    float nn0 = 0.f, nn1 = 0.f;
    if (c + 1 < NC) {
      // issue next-chunk M loads (latency hides under compute below)
      const float* Mn = Mbuf + ((size_t)(c + 1) * 16 + h) * 4096;
#pragma unroll
      for (int i = 0; i < 8; i++) {
        int sl = tid * 8 + i;
        mn[i] = *(const f32x4*)(Mn + (sl >> 4) * 64 + (sl & 15) * 4);
      }
      const float* Nn = NTbuf + ((size_t)(c + 1) * 16 + h) * 4096;
      nn0 = Nn[c0 * 64 + l]; nn1 = Nn[c1 * 64 + l];
    }
    float acc0 = n0, acc1 = n1;
#pragma unroll
    for (int q = 0; q < 16; q++) {
      f32x4 mv = *(const f32x4*)&Ms[p][l][4 * q];
      f32x4 sv0 = *(const f32x4*)&Ssh[p][2 * wv][4 * q];
      f32x4 sv1 = *(const f32x4*)&Ssh[p][2 * wv + 1][4 * q];
#pragma unroll
      for (int t = 0; t < 4; t++) { acc0 += mv[t] * sv0[t]; acc1 += mv[t] * sv1[t]; }
    }
    s0 = acc0; s1 = acc1;
    Ssh[p ^ 1][2 * wv][l] = s0; Ssh[p ^ 1][2 * wv + 1][l] = s1;
    if (c + 1 < NC) {
#pragma unroll
      for (int i = 0; i < 8; i++) {
        int sl = tid * 8 + i;
        *(f32x4*)&Ms[p ^ 1][sl >> 4][(sl & 15) * 4] = mn[i];
      }
    }
    __syncthreads();
    p ^= 1;
    n0 = nn0; n1 = nn1;
  }
}

// phase C (with phaseB2 fused in):
//   kTc: k -> S0 ; Ul: W^T -> U (U = Uv - W*S0). pass2 byte-identical.
__global__ __launch_bounds__(256) void phaseC_kernel(const float* __restrict__ P,
    const float* __restrict__ cumbuf, const u16* __restrict__ Wbuf,
    const u16* __restrict__ Uvbuf, const u16* __restrict__ S0Tbuf,
    const float* __restrict__ nw, u16* __restrict__ ybuf) {
  const int c = blockIdx.x, h = blockIdx.y, tid = threadIdx.x;
  const int rb = tid >> 4, jb = tid & 15;
  __shared__ float qT[64][36];    // [d][r]; reused as ol[32][68]
  __shared__ float kTc[64][68];   // k[d][j] -> S0l[m][d]
  __shared__ float Ul[64][68];    // WTl[m][i] -> U[j][d]
  __shared__ float PmT[64][36];
  __shared__ float cuml[64], nwl[64];
  const size_t base = (size_t)c * 16 + h;
  for (int e = tid; e < 2048; e += 256) {
    int r = e >> 6, d = e & 63;
    qT[d][r] = P[(size_t)(c * 32 + r) * NP + h * 64 + d];
  }
  for (int e = tid; e < 4096; e += 256) {
    int j = e >> 6, d = e & 63, s = c * 64 + j, t = s >> 1, nh = s & 1;
    kTc[d][j] = P[(size_t)t * NP + 1024 + nh * 1024 + h * 64 + d];
  }
  if (tid < 64) { cuml[tid] = cumbuf[base * 64 + tid]; nwl[tid] = nw[tid]; }
  __syncthreads();
  // ---- pass1: QK^T -> PmT ----
  {
    float pa[2][4] = {};
#pragma unroll 4
    for (int d = 0; d < 64; d++) {
      f32x2 qv = *(const f32x2*)&qT[d][2 * rb];
      f32x4 kv = *(const f32x4*)&kTc[d][4 * jb];
#pragma unroll
      for (int rr = 0; rr < 2; rr++)
#pragma unroll
        for (int cc = 0; cc < 4; cc++) pa[rr][cc] += qv[rr] * kv[cc];
    }
#pragma unroll
    for (int rr = 0; rr < 2; rr++)
#pragma unroll
      for (int cc = 0; cc < 4; cc++) {
        int r = 2 * rb + rr, i = 2 * r + 1, j = 4 * jb + cc;
        PmT[j][r] = (j <= i) ? expf(cuml[i] - cuml[j]) * pa[rr][cc] : 0.f;
      }
  }
  __syncthreads();
  // ---- stage2: kTc <- S0, Ul <- W^T ----
  for (int e = tid; e < 4096; e += 256) {
    int i = e >> 6, m = e & 63;
    kTc[m][i] = bf2f(S0Tbuf[base * 4096 + e]);
    Ul[m][i]  = bf2f(Wbuf[base * 4096 + e]);
  }
  __syncthreads();
  // ---- B2 compute: acc = W*S0 ----
  float b2acc[4][4] = {};
  {
#pragma unroll 4
    for (int m = 0; m < 64; m++) {
      f32x4 wv = *(const f32x4*)&Ul[m][4 * rb];
      f32x4 sv = *(const f32x4*)&kTc[m][4 * jb];
#pragma unroll
      for (int rr = 0; rr < 4; rr++)
#pragma unroll
        for (int cc = 0; cc < 4; cc++) b2acc[rr][cc] += wv[rr] * sv[cc];
    }
  }
  __syncthreads();   // W^T reads done before U overwrite
  // ---- U write into Ul ----
#pragma unroll
  for (int rr = 0; rr < 4; rr++) {
    int i = 4 * rb + rr;
    u16x4 uv = *(const u16x4*)&Uvbuf[base * 4096 + (size_t)i * 64 + 4 * jb];
#pragma unroll
    for (int cc = 0; cc < 4; cc++)
      Ul[i][4 * jb + cc] = bf2f(f2bf(bf2f(uv[cc]) - b2acc[rr][cc]));
  }
  __syncthreads();
  // ---- pass2 ----
  float o[2][4];
  {
    float a1[2][4] = {}, a2[2][4] = {};
#pragma unroll 4
    for (int m = 0; m < 64; m++) {
      f32x2 qv = *(const f32x2*)&qT[m][2 * rb];
      f32x4 sv = *(const f32x4*)&kTc[m][4 * jb];
#pragma unroll
      for (int rr = 0; rr < 2; rr++)
#pragma unroll
        for (int cc = 0; cc < 4; cc++) a1[rr][cc] += qv[rr] * sv[cc];
    }
    // triangular: PmT[j][r]=0 for j>2r+1; max needed j = 4rb+3
#pragma unroll 4
    for (int j = 0; j < 4 * rb + 4; j++) {
      f32x2 pv = *(const f32x2*)&PmT[j][2 * rb];
      f32x4 uv = *(const f32x4*)&Ul[j][4 * jb];
#pragma unroll
      for (int rr = 0; rr < 2; rr++)
#pragma unroll
        for (int cc = 0; cc < 4; cc++) a2[rr][cc] += pv[rr] * uv[cc];
    }
#pragma unroll
    for (int rr = 0; rr < 2; rr++) {
      float ec = expf(cuml[2 * (2 * rb + rr) + 1]);
#pragma unroll
      for (int cc = 0; cc < 4; cc++) o[rr][cc] = a1[rr][cc] * ec + a2[rr][cc];
    }
  }
  __syncthreads();
  float* ol = &qT[0][0];   // [32][68]
#pragma unroll
  for (int rr = 0; rr < 2; rr++)
#pragma unroll
    for (int cc = 0; cc < 4; cc++)
      ol[(2 * rb + rr) * 68 + 4 * jb + cc] = o[rr][cc];
  __syncthreads();
  for (int e = tid; e < 2048; e += 256) {
    int r = e >> 6, d = e & 63;
    float ov = ol[r * 68 + d];
    float ss = ov * ov;
#pragma unroll
    for (int off = 32; off; off >>= 1) ss += __shfl_xor(ss, off);
    float on = ov * rsqrtf(ss * (1.f / 64.f) + 1e-5f) * nwl[d];
    int t = c * 32 + r;
    float gt = P[(size_t)t * NP + 5168 + h * 64 + d];
    float sw = gt / (1.f + expf(-gt));
    ybuf[(size_t)t * 1024 + h * 64 + d] = f2bf(on * sw);
  }
}

extern "C" void kernel_launch(void* const* d_in, const int* in_sizes, int n_in,
                              void* d_out, int out_size, void* d_ws, size_t ws_size,
                              hipStream_t stream) {
  const float* x       = (const float*)d_in[0];
  const float* Wq      = (const float*)d_in[1];
  const float* Wk      = (const float*)d_in[2];
  const float* Wv      = (const float*)d_in[3];
  const float* Wb      = (const float*)d_in[4];
  const float* Wa      = (const float*)d_in[5];
  const float* A_log   = (const float*)d_in[6];
  const float* dt_bias = (const float*)d_in[7];
  const float* Wg      = (const float*)d_in[8];
  const float* nw      = (const float*)d_in[9];
  const float* Wo      = (const float*)d_in[10];
  float* out = (float*)d_out;

  char* w = (char*)d_ws;
  size_t used = 0;
  auto alloc = [&](size_t bytes) {
    char* p = w + used; used += (bytes + 255) & ~(size_t)255; return p;
  };
  u16*   xb    = (u16*)  alloc(2048UL * 1024 * 2);
  u16*   WT    = (u16*)  alloc(6272UL * 1024 * 2);   // padded to 49*128 rows
  u16*   WoT   = (u16*)  alloc(1024UL * 1024 * 2);
  float* P     = (float*)alloc(2048UL * NP * 4);
  float* betab = (float*)alloc(4096UL * 16 * 4);
  float* gbuf  = (float*)alloc(2048UL * 16 * 4);
  u16*   ybuf  = (u16*)  alloc(2048UL * 1024 * 2);
  u16*   Wbuf  = (u16*)  alloc((size_t)NC * 16 * 4096 * 2);
  u16*   Uvbuf = (u16*)  alloc((size_t)NC * 16 * 4096 * 2);
  u16*   S0Tb  = (u16*)  alloc((size_t)NC * 16 * 4096 * 2);
  float* Mbuf  = (float*)alloc((size_t)NC * 16 * 4096 * 4);
  float* NTbuf = (float*)alloc((size_t)NC * 16 * 4096 * 4);
  float* cumb  = (float*)alloc((size_t)NC * 16 * 64 * 4);

  auto tgrid = [](long n) { return dim3((unsigned)((n + 255) / 256)); };
  if (used > ws_size) {
    beacon_kernel<<<tgrid(out_size), 256, 0, stream>>>(out, out_size);
    return;
  }

  // zero pad rows 6192..6271 (edge tile of the 128-wide gemm reads them)
  hipMemsetAsync(WT + 6192UL * 1024, 0, 80UL * 1024 * 2, stream);

  cvt_kernel<<<tgrid(2048L*1024), 256, 0, stream>>>(x, xb, 2048L * 1024);
  transAll_kernel<<<dim3(226, 32), 256, 0, stream>>>(Wq, Wk, Wv, Wb, Wa, Wg, Wo, WT, WoT);

  // P (fp32) = xb @ [Wq|Wk|Wv|Wb|Wa|Wg], q/k L2-norm fused in epilogue
  gemm128<<<dim3(16, 49), 256, 0, stream>>>(xb, WT, P, nullptr, 1024, 1024, NP, NP, 0, 1);
  prep_bg_kernel<<<dim3(128), 256, 0, stream>>>(P, A_log, dt_bias, betab, gbuf);

  phaseA_kernel<<<dim3(NC, 16), 256, 0, stream>>>(P, betab, gbuf, Wbuf, Uvbuf, Mbuf, NTbuf, cumb);
  phaseB_kernel<<<dim3(16, 16), 128, 0, stream>>>(Mbuf, NTbuf, S0Tb);
  phaseC_kernel<<<dim3(NC, 16), 256, 0, stream>>>(P, cumb, Wbuf, Uvbuf, S0Tb, nw, ybuf);

  // out (fp32) = ybuf @ Wo (64x128 tiles: 256 blocks = 1/CU)
  gemm64<<<dim3(32, 8), 128, 0, stream>>>(ybuf, WoT, out, 1024, 1024, 1024);
}

// Round 13
// 380.772 us; speedup vs baseline: 1.1805x; 1.0072x over previous
//
#include <hip/hip_runtime.h>
#include <stdint.h>

// ---------------------------------------------------------------------------
// DeltaNet (gated delta rule) forward, MI355X gfx950. Round 25.
// Round 24: 383.5us (norm fused into gemm1; gemm64 256 blocks). This round
// (all bit-exact -> absmax stays 0.04296875):
//  1) prep_bg fused into gemm1 epilogue: by==40 tile's wc=0 quadrants hold
//     beta (j=0,1, h=r) and a-pre (j=2) columns as fp32 acc == the P values
//     prep_bg re-read. Kernel deleted.
//  2) Staging vectorization (G13): phaseC stage2 u16 scalar -> u16x4;
//     phaseC q/k and phaseA k/v stages f32 scalar -> f32x4. Same values,
//     same LDS destinations -> bit-exact.
// P column map: [0,1024) q | [1024,3072) k | [3072,5120) v |
//   [5120,5152) beta-pre | [5152,5168) a-pre | [5168,6192) gate | pad
// ---------------------------------------------------------------------------

typedef unsigned short u16;
typedef __attribute__((ext_vector_type(8))) short bf16x8;
typedef __attribute__((ext_vector_type(4))) float f32x4;
typedef __attribute__((ext_vector_type(2))) float f32x2;
typedef __attribute__((ext_vector_type(4))) unsigned short u16x4;

#define TT 2048
#define NP 6208
#define NC 64
#define CS 64

__device__ __forceinline__ u16 f2bf(float f) {
  union { float f; uint32_t u; } v; v.f = f;
  uint32_t r = v.u + 0x7fffu + ((v.u >> 16) & 1u);  // RNE
  return (u16)(r >> 16);
}
__device__ __forceinline__ float bf2f(u16 b) {
  union { uint32_t u; float f; } v; v.u = ((uint32_t)b) << 16; return v.f;
}

// async global->LDS, 16B per lane; LDS dest = wave-uniform base + lane*16
__device__ __forceinline__ void gload_lds16(const u16* g, u16* l) {
  __builtin_amdgcn_global_load_lds(
      (__attribute__((address_space(1))) const void*)(uintptr_t)g,
      (__attribute__((address_space(3))) void*)(uint32_t)(uintptr_t)l, 16, 0, 0);
}

__global__ void cvt_kernel(const float* __restrict__ src, u16* __restrict__ dst, long n) {
  long i = (long)blockIdx.x * 256 + threadIdx.x;
  if (i < n) dst[i] = f2bf(src[i]);
}

// fused transpose+convert of all 7 weight matrices (rows always 1024)
__global__ __launch_bounds__(256) void transAll_kernel(
    const float* __restrict__ Wq, const float* __restrict__ Wk,
    const float* __restrict__ Wv, const float* __restrict__ Wb,
    const float* __restrict__ Wa, const float* __restrict__ Wg,
    const float* __restrict__ Wo, u16* __restrict__ WT, u16* __restrict__ WoT) {
  int bx = blockIdx.x;
  const float* src; u16* dst; int cols;
  if      (bx < 32)  { src = Wq; dst = WT;                cols = 1024; }
  else if (bx < 96)  { src = Wk; dst = WT + 1024UL*1024;  cols = 2048; bx -= 32; }
  else if (bx < 160) { src = Wv; dst = WT + 3072UL*1024;  cols = 2048; bx -= 96; }
  else if (bx < 161) { src = Wb; dst = WT + 5120UL*1024;  cols = 32;   bx -= 160; }
  else if (bx < 162) { src = Wa; dst = WT + 5152UL*1024;  cols = 16;   bx -= 161; }
  else if (bx < 194) { src = Wg; dst = WT + 5168UL*1024;  cols = 1024; bx -= 162; }
  else               { src = Wo; dst = WoT;               cols = 1024; bx -= 194; }
  __shared__ float tile[32][33];
  const int tx = threadIdx.x & 31, ty = threadIdx.x >> 5;
  const int c0 = bx * 32, r0 = blockIdx.y * 32;
  for (int rr = ty; rr < 32; rr += 8)
    if (c0 + tx < cols) tile[rr][tx] = src[(size_t)(r0 + rr) * cols + c0 + tx];
  __syncthreads();
  for (int rr = ty; rr < 32; rr += 8)
    if (c0 + rr < cols) dst[(size_t)(c0 + rr) * 1024 + r0 + tx] = f2bf(tile[tx][rr]);
}

__global__ __launch_bounds__(256) void beacon_kernel(float* __restrict__ out, int n) {
  int i = blockIdx.x * 256 + threadIdx.x;
  if (i < n) out[i] = 4000.0f;
}

// 128x128-tile GEMM: C = A[M,K](bf16,lda) * BT[N,K]^T(bf16, row stride K).
// 4 waves, each a 64x64 quadrant. BT must be zero-padded to grid.y*128 rows.
// do_norm: q/k head-row L2-norm in epilogue (by<8 scale 0.125; 8<=by<24).
// by==40 wc=0 quadrants also emit betab/gbuf from fp32 acc (== old prep_bg).
__global__ __launch_bounds__(256) void gemm128(const u16* __restrict__ A,
    const u16* __restrict__ BT, float* __restrict__ Cf, u16* __restrict__ Cb,
    int K, int lda, int ldc, int Nmax, int out_bf16, int do_norm,
    const float* __restrict__ A_log, const float* __restrict__ dt_bias,
    float* __restrict__ betab, float* __restrict__ gbuf) {
  const int bm = blockIdx.x * 128, bn = blockIdx.y * 128;
  const int tid = threadIdx.x, w = tid >> 6, lane = tid & 63;
  const int wr = (w >> 1) * 64, wc = (w & 1) * 64;
  const int quad = lane >> 4, r = lane & 15;
  __shared__ u16 As[128][32], Bs[128][32];   // linear: global_load_lds dest
  f32x4 acc[4][4] = {};
  // wave w stages rows w*32..w*32+31 (two 16-row instructions)
  const int sr = w * 32 + (lane >> 2);       // global row for inst 0
  const int sc = (lane & 3) * 8;             // u16 col offset within 32-wide tile
  const u16* gA0 = A  + (size_t)(bm + sr) * lda + sc;
  const u16* gA1 = A  + (size_t)(bm + sr + 16) * lda + sc;
  const u16* gB0 = BT + (size_t)(bn + sr) * K + sc;
  const u16* gB1 = BT + (size_t)(bn + sr + 16) * K + sc;
  u16* lA0 = &As[w * 32][0];
  u16* lA1 = &As[w * 32 + 16][0];
  u16* lB0 = &Bs[w * 32][0];
  u16* lB1 = &Bs[w * 32 + 16][0];
  for (int ks = 0; ks < K; ks += 32) {
    __syncthreads();   // prev-iter readers done before LDS overwrite
    gload_lds16(gA0 + ks, lA0);
    gload_lds16(gA1 + ks, lA1);
    gload_lds16(gB0 + ks, lB0);
    gload_lds16(gB1 + ks, lB1);
    __syncthreads();   // compiler drains vmcnt(0) before barrier
    bf16x8 af[4], bf[4];
#pragma unroll
    for (int i = 0; i < 4; i++) af[i] = *(const bf16x8*)&As[wr + i * 16 + r][quad * 8];
#pragma unroll
    for (int j = 0; j < 4; j++) bf[j] = *(const bf16x8*)&Bs[wc + j * 16 + r][quad * 8];
#pragma unroll
    for (int i = 0; i < 4; i++)
#pragma unroll
      for (int j = 0; j < 4; j++)
        acc[i][j] = __builtin_amdgcn_mfma_f32_16x16x32_bf16(af[i], bf[j], acc[i][j], 0, 0, 0);
  }
  // fused L2-norm: wave quadrant = one 64-col head; per row d = j*16 + r.
  // prep's butterfly (off 32,16,8,4,2,1 on d) == reg pairs (j^2 then j^1)
  // then shfl_xor 8,4,2,1 (all within the 16-lane quad group = one row).
  int mode = 0;
  if (do_norm) { if (blockIdx.y < 8) mode = 1; else if (blockIdx.y < 24) mode = 2; }
  if (mode) {
#pragma unroll
    for (int i = 0; i < 4; i++)
#pragma unroll
      for (int rg = 0; rg < 4; rg++) {
        float a0 = acc[i][0][rg], a1 = acc[i][1][rg];
        float a2 = acc[i][2][rg], a3 = acc[i][3][rg];
        float ss = (a0 * a0 + a2 * a2) + (a1 * a1 + a3 * a3);
        ss += __shfl_xor(ss, 8);
        ss += __shfl_xor(ss, 4);
        ss += __shfl_xor(ss, 2);
        ss += __shfl_xor(ss, 1);
        float rs = rsqrtf(ss + 1e-6f);
#pragma unroll
        for (int j = 0; j < 4; j++) {
          float ov = acc[i][j][rg] * rs;
          if (mode == 1) ov *= 0.125f;
          acc[i][j][rg] = ov;
        }
      }
  }
  // fused beta/g: by==40, wc=0 quadrants hold cols 5120+j*16+r.
  // j=0 -> beta nh=0 (h=r), j=1 -> beta nh=1, j=2 -> a-pre. acc fp32 ==
  // the P value the old prep_bg kernel re-read -> bit-exact.
  if (do_norm && blockIdx.y == 40 && (w & 1) == 0) {
    const float al = A_log[r], db = dt_bias[r];
#pragma unroll
    for (int i = 0; i < 4; i++)
#pragma unroll
      for (int rg = 0; rg < 4; rg++) {
        int t = bm + wr + i * 16 + quad * 4 + rg;
        float b0 = acc[i][0][rg], b1 = acc[i][1][rg];
        betab[(size_t)(2 * t) * 16 + r]     = 2.f / (1.f + expf(-b0));
        betab[(size_t)(2 * t + 1) * 16 + r] = 2.f / (1.f + expf(-b1));
        float a = acc[i][2][rg] + db;
        float sp = (a > 20.f) ? a : log1pf(expf(a));
        gbuf[t * 16 + r] = -expf(al) * sp;
      }
  }
#pragma unroll
  for (int i = 0; i < 4; i++)
#pragma unroll
    for (int j = 0; j < 4; j++)
#pragma unroll
      for (int rg = 0; rg < 4; rg++) {
        int row = bm + wr + i * 16 + quad * 4 + rg;
        int col = bn + wc + j * 16 + r;
        if (col < Nmax) {
          float v = acc[i][j][rg];
          if (out_bf16) Cb[(size_t)row * ldc + col] = f2bf(v);
          else          Cf[(size_t)row * ldc + col] = v;
        }
      }
}

// 64x128-tile GEMM for the output projection: 2 waves, 256 blocks (1/CU).
// Same per-output mfma K-chain as gemm128 (bit-exact).
__global__ __launch_bounds__(128) void gemm64(const u16* __restrict__ A,
    const u16* __restrict__ BT, float* __restrict__ C, int K, int lda, int ldc) {
  const int bm = blockIdx.x * 64, bn = blockIdx.y * 128;
  const int tid = threadIdx.x, w = tid >> 6, lane = tid & 63;
  const int wc = w * 64;
  const int quad = lane >> 4, r = lane & 15;
  __shared__ u16 As[64][32], Bs[128][32];
  f32x4 acc[4][4] = {};
  const int lr = lane >> 2;          // staging row within 16-row group
  const int sc = (lane & 3) * 8;
  for (int ks = 0; ks < K; ks += 32) {
    __syncthreads();
    if (w == 0) {
      gload_lds16(A  + (size_t)(bm +  0 + lr) * lda + ks + sc, &As[0][0]);
      gload_lds16(A  + (size_t)(bm + 16 + lr) * lda + ks + sc, &As[16][0]);
      gload_lds16(A  + (size_t)(bm + 32 + lr) * lda + ks + sc, &As[32][0]);
      gload_lds16(A  + (size_t)(bm + 48 + lr) * lda + ks + sc, &As[48][0]);
      gload_lds16(BT + (size_t)(bn +  0 + lr) * K + ks + sc, &Bs[0][0]);
      gload_lds16(BT + (size_t)(bn + 16 + lr) * K + ks + sc, &Bs[16][0]);
    } else {
      gload_lds16(BT + (size_t)(bn +  32 + lr) * K + ks + sc, &Bs[32][0]);
      gload_lds16(BT + (size_t)(bn +  48 + lr) * K + ks + sc, &Bs[48][0]);
      gload_lds16(BT + (size_t)(bn +  64 + lr) * K + ks + sc, &Bs[64][0]);
      gload_lds16(BT + (size_t)(bn +  80 + lr) * K + ks + sc, &Bs[80][0]);
      gload_lds16(BT + (size_t)(bn +  96 + lr) * K + ks + sc, &Bs[96][0]);
      gload_lds16(BT + (size_t)(bn + 112 + lr) * K + ks + sc, &Bs[112][0]);
    }
    __syncthreads();
    bf16x8 af[4], bf[4];
#pragma unroll
    for (int i = 0; i < 4; i++) af[i] = *(const bf16x8*)&As[i * 16 + r][quad * 8];
#pragma unroll
    for (int j = 0; j < 4; j++) bf[j] = *(const bf16x8*)&Bs[wc + j * 16 + r][quad * 8];
#pragma unroll
    for (int i = 0; i < 4; i++)
#pragma unroll
      for (int j = 0; j < 4; j++)
        acc[i][j] = __builtin_amdgcn_mfma_f32_16x16x32_bf16(af[i], bf[j], acc[i][j], 0, 0, 0);
  }
#pragma unroll
  for (int i = 0; i < 4; i++)
#pragma unroll
    for (int j = 0; j < 4; j++)
#pragma unroll
      for (int rg = 0; rg < 4; rg++)
        C[(size_t)(bm + i * 16 + quad * 4 + rg) * ldc + bn + wc + j * 16 + r] = acc[i][j][rg];
}

// phase A: per (c,h): G, T, W(bf16), M(fp32), Uv(bf16), NT(fp32), cum.
// 3 LDS arrays (53248 B -> 3 blocks/CU): LA: kT->Tt->Uv, LB: kf, LC: Sc->v->W.
// r13 structure; k/v staging vectorized to f32x4 (same values/destinations).
__global__ __launch_bounds__(256, 1) void phaseA_kernel(const float* __restrict__ P,
    const float* __restrict__ betab, const float* __restrict__ gbuf,
    u16* __restrict__ Wbuf, u16* __restrict__ Uvbuf,
    float* __restrict__ Mbuf, float* __restrict__ NTbuf, float* __restrict__ cumbuf) {
  const int c = blockIdx.x, h = blockIdx.y, tid = threadIdx.x;
  const int bi = tid >> 4, bj = tid & 15;
  __shared__ float LA[64][68];   // kT -> Tt -> Uv
  __shared__ float LB[64][68];   // kf (persistent)
  __shared__ float LC[64][68];   // Sc -> v -> W
  __shared__ float cumch[64], betach[64], bbch[64], rowfl[64];
  const size_t base = ((size_t)c * 16 + h) * 4096;
  const int rq = tid >> 4, dq = (tid & 15) * 4;   // f32x4 staging map

  {
#pragma unroll
    for (int s = 0; s < 4; s++) {
      int i = rq + 16 * s, sg = c * 64 + i, t = sg >> 1, nh = sg & 1;
      f32x4 kv = *(const f32x4*)&P[(size_t)t * NP + 1024 + nh * 1024 + h * 64 + dq];
      *(f32x4*)&LB[i][dq] = kv;
      LA[dq + 0][i] = kv[0];
      LA[dq + 1][i] = kv[1];
      LA[dq + 2][i] = kv[2];
      LA[dq + 3][i] = kv[3];
    }
  }
  if (tid < 64) betach[tid] = betab[(size_t)(c * 64 + tid) * 16 + h];
  __syncthreads();
  if (tid == 0) {
    float cum = 0.f;
    for (int i = 0; i < 64; i++) {
      if ((i & 1) == 0) cum += gbuf[(c * 32 + (i >> 1)) * 16 + h];
      cumch[i] = cum;
    }
  }
  __syncthreads();
  if (tid < 64) {
    bbch[tid] = betach[tid] * expf(cumch[tid]);
    rowfl[tid] = expf(cumch[63] - cumch[tid]);
  }
  // G then scale -> LC
  {
    float acc[4][4] = {};
#pragma unroll 4
    for (int d = 0; d < 64; d++) {
      f32x4 a = *(const f32x4*)&LA[d][4 * bi];
      f32x4 b = *(const f32x4*)&LA[d][4 * bj];
#pragma unroll
      for (int rr = 0; rr < 4; rr++)
#pragma unroll
        for (int cc = 0; cc < 4; cc++) acc[rr][cc] += a[rr] * b[cc];
    }
#pragma unroll
    for (int rr = 0; rr < 4; rr++)
#pragma unroll
      for (int cc = 0; cc < 4; cc++) {
        int i = 4 * bi + rr, j = 4 * bj + cc;
        LC[i][j] = (j < i) ? betach[i] * expf(cumch[i] - cumch[j]) * acc[rr][cc] : 0.f;
      }
  }
  __syncthreads();
  // T = (I+A)^-1 forward substitution: LC(Sc) -> LA[j][i] (Tt)
  {
    int col = tid >> 2, part = tid & 3;
    if (part == 0) LA[col][0] = (col == 0) ? 1.f : 0.f;
    for (int i = 1; i < 64; i++) {
      float partial = 0.f;
      for (int j = col + part; j < i; j += 4) partial += LC[i][j] * LA[col][j];
      partial += __shfl_xor(partial, 1);
      partial += __shfl_xor(partial, 2);
      if (part == 0) LA[col][i] = ((i == col) ? 1.f : 0.f) - partial;
    }
  }
  __syncthreads();
  // prefetch v into regs now (f32x4); ds_write after M (hides under W+M)
  f32x4 vreg4[4];
  {
#pragma unroll
    for (int s = 0; s < 4; s++) {
      int i = rq + 16 * s, sg = c * 64 + i, t = sg >> 1, nh = sg & 1;
      vreg4[s] = *(const f32x4*)&P[(size_t)t * NP + 3072 + nh * 1024 + h * 64 + dq];
    }
  }
  // W[i][d] = sum_{j<=i} T[i][j]*bb[j]*k[j][d]  (triangular trip)
  {
    float acc[4][4] = {};
#pragma unroll 4
    for (int j = 0; j < 4 * bi + 4; j++) {
      f32x4 tv = *(const f32x4*)&LA[j][4 * bi];
      f32x4 kv = *(const f32x4*)&LB[j][4 * bj];
      float bbj = bbch[j];
#pragma unroll
      for (int rr = 0; rr < 4; rr++)
#pragma unroll
        for (int cc = 0; cc < 4; cc++) acc[rr][cc] += tv[rr] * bbj * kv[cc];
    }
#pragma unroll
    for (int rr = 0; rr < 4; rr++) {
      int i = 4 * bi + rr;
      u16x4 wb;
#pragma unroll
      for (int cc = 0; cc < 4; cc++) { LC[i][4 * bj + cc] = acc[rr][cc]; wb[cc] = f2bf(acc[rr][cc]); }
      *(u16x4*)&Wbuf[base + (size_t)i * 64 + 4 * bj] = wb;
    }
  }
  __syncthreads();
  // M[m][mm] = bL*delta - sum_i rowf[i]*k[i][m]*W[i][mm]
  {
    const float bL = expf(cumch[63]);
    float acc[4][4] = {};
#pragma unroll 4
    for (int i = 0; i < 64; i++) {
      f32x4 kv = *(const f32x4*)&LB[i][4 * bi];
      f32x4 wv = *(const f32x4*)&LC[i][4 * bj];
      float rf = rowfl[i];
#pragma unroll
      for (int rr = 0; rr < 4; rr++)
#pragma unroll
        for (int cc = 0; cc < 4; cc++) acc[rr][cc] += rf * kv[rr] * wv[cc];
    }
#pragma unroll
    for (int rr = 0; rr < 4; rr++) {
      int m = 4 * bi + rr;
      f32x4 mv;
#pragma unroll
      for (int cc = 0; cc < 4; cc++)
        mv[cc] = ((m == 4 * bj + cc) ? bL : 0.f) - acc[rr][cc];
      *(f32x4*)&Mbuf[base + (size_t)m * 64 + 4 * bj] = mv;
    }
  }
  __syncthreads();
  // stage v (from regs) over LC
  {
#pragma unroll
    for (int s = 0; s < 4; s++) *(f32x4*)&LC[rq + 16 * s][dq] = vreg4[s];
  }
  __syncthreads();
  // Uv[i][d] = sum_{j<=i} T[i][j]*beta[j]*v[j][d] -> regs (LA still = Tt)
  float ua[4][4] = {};
  {
#pragma unroll 4
    for (int j = 0; j < 4 * bi + 4; j++) {
      f32x4 tv = *(const f32x4*)&LA[j][4 * bi];
      f32x4 vv = *(const f32x4*)&LC[j][4 * bj];
      float be = betach[j];
#pragma unroll
      for (int rr = 0; rr < 4; rr++)
#pragma unroll
        for (int cc = 0; cc < 4; cc++) ua[rr][cc] += tv[rr] * be * vv[cc];
    }
  }
  __syncthreads();   // all Tt reads complete before overwrite
  {
#pragma unroll
    for (int rr = 0; rr < 4; rr++) {
      int i = 4 * bi + rr;
      u16x4 ub;
#pragma unroll
      for (int cc = 0; cc < 4; cc++) { LA[i][4 * bj + cc] = ua[rr][cc]; ub[cc] = f2bf(ua[rr][cc]); }
      *(u16x4*)&Uvbuf[base + (size_t)i * 64 + 4 * bj] = ub;
    }
  }
  __syncthreads();
  // NT[d][m] = sum_i rowf[i]*k[i][m]*Uv[i][d]
  {
    float acc[4][4] = {};
#pragma unroll 4
    for (int i = 0; i < 64; i++) {
      f32x4 kv = *(const f32x4*)&LB[i][4 * bi];
      f32x4 uv = *(const f32x4*)&LA[i][4 * bj];
      float rf = rowfl[i];
#pragma unroll
      for (int rr = 0; rr < 4; rr++)
#pragma unroll
        for (int cc = 0; cc < 4; cc++) acc[rr][cc] += rf * kv[rr] * uv[cc];
    }
#pragma unroll
    for (int cc = 0; cc < 4; cc++) {
      f32x4 nv;
#pragma unroll
      for (int rr = 0; rr < 4; rr++) nv[rr] = acc[rr][cc];
      *(f32x4*)&NTbuf[base + (size_t)(4 * bj + cc) * 64 + 4 * bi] = nv;
    }
  }
  if (tid < 64) cumbuf[((size_t)c * 16 + h) * 64 + tid] = cumch[tid];
}

// phase B v2 (r21): 4 cols/block, 2 waves; M chunk staged once into LDS
// (dbuf, pad-68) and shared by both waves -> 256 blocks (1/CU), 256MB M
// traffic. Per-column math/order identical to r13 (bit-exact).
__global__ __launch_bounds__(128) void phaseB_kernel(const float* __restrict__ Mbuf,
    const float* __restrict__ NTbuf, u16* __restrict__ S0Tbuf) {
  const int g = blockIdx.x, h = blockIdx.y;
  const int tid = threadIdx.x, wv = tid >> 6, l = tid & 63;
  const int c0 = 4 * g + 2 * wv, c1 = c0 + 1;
  __shared__ float Ms[2][64][68];
  __shared__ float Ssh[2][4][64];
  float s0 = 0.f, s1 = 0.f;
  float n0, n1;
  f32x4 mn[8];
  // stage chunk 0: thread t covers f32x4-slots t*8..t*8+7 (row=slot>>4, s=slot&15)
  {
    const float* Mc = Mbuf + (size_t)h * 4096;
#pragma unroll
    for (int i = 0; i < 8; i++) {
      int sl = tid * 8 + i;
      mn[i] = *(const f32x4*)(Mc + (sl >> 4) * 64 + (sl & 15) * 4);
    }
#pragma unroll
    for (int i = 0; i < 8; i++) {
      int sl = tid * 8 + i;
      *(f32x4*)&Ms[0][sl >> 4][(sl & 15) * 4] = mn[i];
    }
    const float* Nc = NTbuf + (size_t)h * 4096;
    n0 = Nc[c0 * 64 + l]; n1 = Nc[c1 * 64 + l];
  }
  Ssh[0][2 * wv][l] = 0.f; Ssh[0][2 * wv + 1][l] = 0.f;
  __syncthreads();
  int p = 0;
  for (int c = 0; c < NC; c++) {
    const size_t base = ((size_t)c * 16 + h) * 4096;
    S0Tbuf[base + (size_t)c0 * 64 + l] = f2bf(s0);
    S0Tbuf[base + (size_t)c1 * 64 + l] = f2bf(s1);
    float nn0 = 0.f, nn1 = 0.f;
    if (c + 1 < NC) {
      // issue next-chunk M loads (latency hides under compute below)
      const float* Mn = Mbuf + ((size_t)(c + 1) * 16 + h) * 4096;
#pragma unroll
      for (int i = 0; i < 8; i++) {
        int sl = tid * 8 + i;
        mn[i] = *(const f32x4*)(Mn + (sl >> 4) * 64 + (sl & 15) * 4);
      }
      const float* Nn = NTbuf + ((size_t)(c + 1) * 16 + h) * 4096;
      nn0 = Nn[c0 * 64 + l]; nn1 = Nn[c1 * 64 + l];
    }
    float acc0 = n0, acc1 = n1;
#pragma unroll
    for (int q = 0; q < 16; q++) {
      f32x4 mv = *(const f32x4*)&Ms[p][l][4 * q];
      f32x4 sv0 = *(const f32x4*)&Ssh[p][2 * wv][4 * q];
      f32x4 sv1 = *(const f32x4*)&Ssh[p][2 * wv + 1][4 * q];
#pragma unroll
      for (int t = 0; t < 4; t++) { acc0 += mv[t] * sv0[t]; acc1 += mv[t] * sv1[t]; }
    }
    s0 = acc0; s1 = acc1;
    Ssh[p ^ 1][2 * wv][l] = s0; Ssh[p ^ 1][2 * wv + 1][l] = s1;
    if (c + 1 < NC) {
#pragma unroll
      for (int i = 0; i < 8; i++) {
        int sl = tid * 8 + i;
        *(f32x4*)&Ms[p ^ 1][sl >> 4][(sl & 15) * 4] = mn[i];
      }
    }
    __syncthreads();
    p ^= 1;
    n0 = nn0; n1 = nn1;
  }
}

// phase C (with phaseB2 fused in):
//   kTc: k -> S0 ; Ul: W^T -> U (U = Uv - W*S0). pass2 byte-identical.
//   Staging vectorized: q/k f32x4, S0/W u16x4 (same values/destinations).
__global__ __launch_bounds__(256) void phaseC_kernel(const float* __restrict__ P,
    const float* __restrict__ cumbuf, const u16* __restrict__ Wbuf,
    const u16* __restrict__ Uvbuf, const u16* __restrict__ S0Tbuf,
    const float* __restrict__ nw, u16* __restrict__ ybuf) {
  const int c = blockIdx.x, h = blockIdx.y, tid = threadIdx.x;
  const int rb = tid >> 4, jb = tid & 15;
  __shared__ float qT[64][36];    // [d][r]; reused as ol[32][68]
  __shared__ float kTc[64][68];   // k[d][j] -> S0l[m][d]
  __shared__ float Ul[64][68];    // WTl[m][i] -> U[j][d]
  __shared__ float PmT[64][36];
  __shared__ float cuml[64], nwl[64];
  const size_t base = (size_t)c * 16 + h;
  for (int c4 = tid; c4 < 512; c4 += 256) {
    int e = c4 * 4, r = e >> 6, d = e & 63;
    f32x4 qv = *(const f32x4*)&P[(size_t)(c * 32 + r) * NP + h * 64 + d];
    qT[d][r] = qv[0]; qT[d + 1][r] = qv[1]; qT[d + 2][r] = qv[2]; qT[d + 3][r] = qv[3];
  }
  for (int c4 = tid; c4 < 1024; c4 += 256) {
    int e = c4 * 4, j = e >> 6, d = e & 63, sg = c * 64 + j, t = sg >> 1, nh = sg & 1;
    f32x4 kv = *(const f32x4*)&P[(size_t)t * NP + 1024 + nh * 1024 + h * 64 + d];
    kTc[d][j] = kv[0]; kTc[d + 1][j] = kv[1]; kTc[d + 2][j] = kv[2]; kTc[d + 3][j] = kv[3];
  }
  if (tid < 64) { cuml[tid] = cumbuf[base * 64 + tid]; nwl[tid] = nw[tid]; }
  __syncthreads();
  // ---- pass1: QK^T -> PmT ----
  {
    float pa[2][4] = {};
#pragma unroll 4
    for (int d = 0; d < 64; d++) {
      f32x2 qv = *(const f32x2*)&qT[d][2 * rb];
      f32x4 kv = *(const f32x4*)&kTc[d][4 * jb];
#pragma unroll
      for (int rr = 0; rr < 2; rr++)
#pragma unroll
        for (int cc = 0; cc < 4; cc++) pa[rr][cc] += qv[rr] * kv[cc];
    }
#pragma unroll
    for (int rr = 0; rr < 2; rr++)
#pragma unroll
      for (int cc = 0; cc < 4; cc++) {
        int r = 2 * rb + rr, i = 2 * r + 1, j = 4 * jb + cc;
        PmT[j][r] = (j <= i) ? expf(cuml[i] - cuml[j]) * pa[rr][cc] : 0.f;
      }
  }
  __syncthreads();
  // ---- stage2: kTc <- S0, Ul <- W^T (u16x4 vectorized) ----
  for (int c4 = tid; c4 < 1024; c4 += 256) {
    int e = c4 * 4, i = e >> 6, m = e & 63;
    u16x4 sv = *(const u16x4*)&S0Tbuf[base * 4096 + e];
    u16x4 wv = *(const u16x4*)&Wbuf[base * 4096 + e];
    kTc[m][i] = bf2f(sv[0]); kTc[m + 1][i] = bf2f(sv[1]);
    kTc[m + 2][i] = bf2f(sv[2]); kTc[m + 3][i] = bf2f(sv[3]);
    Ul[m][i] = bf2f(wv[0]); Ul[m + 1][i] = bf2f(wv[1]);
    Ul[m + 2][i] = bf2f(wv[2]); Ul[m + 3][i] = bf2f(wv[3]);
  }
  __syncthreads();
  // ---- B2 compute: acc = W*S0 ----
  float b2acc[4][4] = {};
  {
#pragma unroll 4
    for (int m = 0; m < 64; m++) {
      f32x4 wv = *(const f32x4*)&Ul[m][4 * rb];
      f32x4 sv = *(const f32x4*)&kTc[m][4 * jb];
#pragma unroll
      for (int rr = 0; rr < 4; rr++)
#pragma unroll
        for (int cc = 0; cc < 4; cc++) b2acc[rr][cc] += wv[rr] * sv[cc];
    }
  }
  __syncthreads();   // W^T reads done before U overwrite
  // ---- U write into Ul ----
#pragma unroll
  for (int rr = 0; rr < 4; rr++) {
    int i = 4 * rb + rr;
    u16x4 uv = *(const u16x4*)&Uvbuf[base * 4096 + (size_t)i * 64 + 4 * jb];
#pragma unroll
    for (int cc = 0; cc < 4; cc++)
      Ul[i][4 * jb + cc] = bf2f(f2bf(bf2f(uv[cc]) - b2acc[rr][cc]));
  }
  __syncthreads();
  // ---- pass2 ----
  float o[2][4];
  {
    float a1[2][4] = {}, a2[2][4] = {};
#pragma unroll 4
    for (int m = 0; m < 64; m++) {
      f32x2 qv = *(const f32x2*)&qT[m][2 * rb];
      f32x4 sv = *(const f32x4*)&kTc[m][4 * jb];
#pragma unroll
      for (int rr = 0; rr < 2; rr++)
#pragma unroll
        for (int cc = 0; cc < 4; cc++) a1[rr][cc] += qv[rr] * sv[cc];
    }
    // triangular: PmT[j][r]=0 for j>2r+1; max needed j = 4rb+3
#pragma unroll 4
    for (int j = 0; j < 4 * rb + 4; j++) {
      f32x2 pv = *(const f32x2*)&PmT[j][2 * rb];
      f32x4 uv = *(const f32x4*)&Ul[j][4 * jb];
#pragma unroll
      for (int rr = 0; rr < 2; rr++)
#pragma unroll
        for (int cc = 0; cc < 4; cc++) a2[rr][cc] += pv[rr] * uv[cc];
    }
#pragma unroll
    for (int rr = 0; rr < 2; rr++) {
      float ec = expf(cuml[2 * (2 * rb + rr) + 1]);
#pragma unroll
      for (int cc = 0; cc < 4; cc++) o[rr][cc] = a1[rr][cc] * ec + a2[rr][cc];
    }
  }
  __syncthreads();
  float* ol = &qT[0][0];   // [32][68]
#pragma unroll
  for (int rr = 0; rr < 2; rr++)
#pragma unroll
    for (int cc = 0; cc < 4; cc++)
      ol[(2 * rb + rr) * 68 + 4 * jb + cc] = o[rr][cc];
  __syncthreads();
  for (int e = tid; e < 2048; e += 256) {
    int r = e >> 6, d = e & 63;
    float ov = ol[r * 68 + d];
    float ss = ov * ov;
#pragma unroll
    for (int off = 32; off; off >>= 1) ss += __shfl_xor(ss, off);
    float on = ov * rsqrtf(ss * (1.f / 64.f) + 1e-5f) * nwl[d];
    int t = c * 32 + r;
    float gt = P[(size_t)t * NP + 5168 + h * 64 + d];
    float sw = gt / (1.f + expf(-gt));
    ybuf[(size_t)t * 1024 + h * 64 + d] = f2bf(on * sw);
  }
}

extern "C" void kernel_launch(void* const* d_in, const int* in_sizes, int n_in,
                              void* d_out, int out_size, void* d_ws, size_t ws_size,
                              hipStream_t stream) {
  const float* x       = (const float*)d_in[0];
  const float* Wq      = (const float*)d_in[1];
  const float* Wk      = (const float*)d_in[2];
  const float* Wv      = (const float*)d_in[3];
  const float* Wb      = (const float*)d_in[4];
  const float* Wa      = (const float*)d_in[5];
  const float* A_log   = (const float*)d_in[6];
  const float* dt_bias = (const float*)d_in[7];
  const float* Wg      = (const float*)d_in[8];
  const float* nw      = (const float*)d_in[9];
  const float* Wo      = (const float*)d_in[10];
  float* out = (float*)d_out;

  char* w = (char*)d_ws;
  size_t used = 0;
  auto alloc = [&](size_t bytes) {
    char* p = w + used; used += (bytes + 255) & ~(size_t)255; return p;
  };
  u16*   xb    = (u16*)  alloc(2048UL * 1024 * 2);
  u16*   WT    = (u16*)  alloc(6272UL * 1024 * 2);   // padded to 49*128 rows
  u16*   WoT   = (u16*)  alloc(1024UL * 1024 * 2);
  float* P     = (float*)alloc(2048UL * NP * 4);
  float* betab = (float*)alloc(4096UL * 16 * 4);
  float* gbuf  = (float*)alloc(2048UL * 16 * 4);
  u16*   ybuf  = (u16*)  alloc(2048UL * 1024 * 2);
  u16*   Wbuf  = (u16*)  alloc((size_t)NC * 16 * 4096 * 2);
  u16*   Uvbuf = (u16*)  alloc((size_t)NC * 16 * 4096 * 2);
  u16*   S0Tb  = (u16*)  alloc((size_t)NC * 16 * 4096 * 2);
  float* Mbuf  = (float*)alloc((size_t)NC * 16 * 4096 * 4);
  float* NTbuf = (float*)alloc((size_t)NC * 16 * 4096 * 4);
  float* cumb  = (float*)alloc((size_t)NC * 16 * 64 * 4);

  auto tgrid = [](long n) { return dim3((unsigned)((n + 255) / 256)); };
  if (used > ws_size) {
    beacon_kernel<<<tgrid(out_size), 256, 0, stream>>>(out, out_size);
    return;
  }

  // zero pad rows 6192..6271 (edge tile of the 128-wide gemm reads them)
  hipMemsetAsync(WT + 6192UL * 1024, 0, 80UL * 1024 * 2, stream);

  cvt_kernel<<<tgrid(2048L*1024), 256, 0, stream>>>(x, xb, 2048L * 1024);
  transAll_kernel<<<dim3(226, 32), 256, 0, stream>>>(Wq, Wk, Wv, Wb, Wa, Wg, Wo, WT, WoT);

  // P (fp32) = xb @ [Wq|Wk|Wv|Wb|Wa|Wg]; q/k norm + beta/g fused in epilogue
  gemm128<<<dim3(16, 49), 256, 0, stream>>>(xb, WT, P, nullptr, 1024, 1024, NP, NP, 0, 1,
                                            A_log, dt_bias, betab, gbuf);

  phaseA_kernel<<<dim3(NC, 16), 256, 0, stream>>>(P, betab, gbuf, Wbuf, Uvbuf, Mbuf, NTbuf, cumb);
  phaseB_kernel<<<dim3(16, 16), 128, 0, stream>>>(Mbuf, NTbuf, S0Tb);
  phaseC_kernel<<<dim3(NC, 16), 256, 0, stream>>>(P, cumb, Wbuf, Uvbuf, S0Tb, nw, ybuf);

  // out (fp32) = ybuf @ Wo (64x128 tiles: 256 blocks = 1/CU)
  gemm64<<<dim3(32, 8), 128, 0, stream>>>(ybuf, WoT, out, 1024, 1024, 1024);
}

// Round 14
// 373.809 us; speedup vs baseline: 1.2025x; 1.0186x over previous
//
#include <hip/hip_runtime.h>
#include <stdint.h>

// ---------------------------------------------------------------------------
// DeltaNet (gated delta rule) forward, MI355X gfx950. Round 26.
// Round 25: 380.8us. This round (all bit-exact -> absmax 0.04296875):
//  1) phaseC T14 async-stage split: S0/W prefetched to regs before pass1,
//     Uv before B2 compute, gate before the ol barrier; LDS writes/uses
//     after the barriers. Same values/destinations -> bit-exact. Removes
//     ~1.5k cycles of serial global-load latency per block.
//  2) cvt fused into transAll (grid bx>=226 does f32x4->u16x4 x-convert;
//     cvt blocks return before any barrier). One fewer launch.
// P column map: [0,1024) q | [1024,3072) k | [3072,5120) v |
//   [5120,5152) beta-pre | [5152,5168) a-pre | [5168,6192) gate | pad
// ---------------------------------------------------------------------------

typedef unsigned short u16;
typedef __attribute__((ext_vector_type(8))) short bf16x8;
typedef __attribute__((ext_vector_type(4))) float f32x4;
typedef __attribute__((ext_vector_type(2))) float f32x2;
typedef __attribute__((ext_vector_type(4))) unsigned short u16x4;

#define TT 2048
#define NP 6208
#define NC 64
#define CS 64

__device__ __forceinline__ u16 f2bf(float f) {
  union { float f; uint32_t u; } v; v.f = f;
  uint32_t r = v.u + 0x7fffu + ((v.u >> 16) & 1u);  // RNE
  return (u16)(r >> 16);
}
__device__ __forceinline__ float bf2f(u16 b) {
  union { uint32_t u; float f; } v; v.u = ((uint32_t)b) << 16; return v.f;
}

// async global->LDS, 16B per lane; LDS dest = wave-uniform base + lane*16
__device__ __forceinline__ void gload_lds16(const u16* g, u16* l) {
  __builtin_amdgcn_global_load_lds(
      (__attribute__((address_space(1))) const void*)(uintptr_t)g,
      (__attribute__((address_space(3))) void*)(uint32_t)(uintptr_t)l, 16, 0, 0);
}

// fused transpose+convert of all 7 weight matrices (rows always 1024);
// bx>=226 blocks instead convert x -> xb (f32x4/u16x4, 1024 el/block).
__global__ __launch_bounds__(256) void transAll_kernel(
    const float* __restrict__ Wq, const float* __restrict__ Wk,
    const float* __restrict__ Wv, const float* __restrict__ Wb,
    const float* __restrict__ Wa, const float* __restrict__ Wg,
    const float* __restrict__ Wo, u16* __restrict__ WT, u16* __restrict__ WoT,
    const float* __restrict__ x, u16* __restrict__ xb) {
  int bx = blockIdx.x;
  if (bx >= 226) {   // cvt path: chunk = (bx-226)*32+by in [0,2048)
    long chunk = (long)(bx - 226) * 32 + blockIdx.y;
    long i4 = chunk * 1024 + threadIdx.x * 4;
    f32x4 v = *(const f32x4*)&x[i4];
    u16x4 o;
#pragma unroll
    for (int c = 0; c < 4; c++) o[c] = f2bf(v[c]);
    *(u16x4*)&xb[i4] = o;
    return;
  }
  const float* src; u16* dst; int cols;
  if      (bx < 32)  { src = Wq; dst = WT;                cols = 1024; }
  else if (bx < 96)  { src = Wk; dst = WT + 1024UL*1024;  cols = 2048; bx -= 32; }
  else if (bx < 160) { src = Wv; dst = WT + 3072UL*1024;  cols = 2048; bx -= 96; }
  else if (bx < 161) { src = Wb; dst = WT + 5120UL*1024;  cols = 32;   bx -= 160; }
  else if (bx < 162) { src = Wa; dst = WT + 5152UL*1024;  cols = 16;   bx -= 161; }
  else if (bx < 194) { src = Wg; dst = WT + 5168UL*1024;  cols = 1024; bx -= 162; }
  else               { src = Wo; dst = WoT;               cols = 1024; bx -= 194; }
  __shared__ float tile[32][33];
  const int tx = threadIdx.x & 31, ty = threadIdx.x >> 5;
  const int c0 = bx * 32, r0 = blockIdx.y * 32;
  for (int rr = ty; rr < 32; rr += 8)
    if (c0 + tx < cols) tile[rr][tx] = src[(size_t)(r0 + rr) * cols + c0 + tx];
  __syncthreads();
  for (int rr = ty; rr < 32; rr += 8)
    if (c0 + rr < cols) dst[(size_t)(c0 + rr) * 1024 + r0 + tx] = f2bf(tile[tx][rr]);
}

__global__ __launch_bounds__(256) void beacon_kernel(float* __restrict__ out, int n) {
  int i = blockIdx.x * 256 + threadIdx.x;
  if (i < n) out[i] = 4000.0f;
}

// 128x128-tile GEMM: C = A[M,K](bf16,lda) * BT[N,K]^T(bf16, row stride K).
// 4 waves, each a 64x64 quadrant. BT must be zero-padded to grid.y*128 rows.
// do_norm: q/k head-row L2-norm in epilogue (by<8 scale 0.125; 8<=by<24).
// by==40 wc=0 quadrants also emit betab/gbuf from fp32 acc (== old prep_bg).
__global__ __launch_bounds__(256) void gemm128(const u16* __restrict__ A,
    const u16* __restrict__ BT, float* __restrict__ Cf, u16* __restrict__ Cb,
    int K, int lda, int ldc, int Nmax, int out_bf16, int do_norm,
    const float* __restrict__ A_log, const float* __restrict__ dt_bias,
    float* __restrict__ betab, float* __restrict__ gbuf) {
  const int bm = blockIdx.x * 128, bn = blockIdx.y * 128;
  const int tid = threadIdx.x, w = tid >> 6, lane = tid & 63;
  const int wr = (w >> 1) * 64, wc = (w & 1) * 64;
  const int quad = lane >> 4, r = lane & 15;
  __shared__ u16 As[128][32], Bs[128][32];   // linear: global_load_lds dest
  f32x4 acc[4][4] = {};
  // wave w stages rows w*32..w*32+31 (two 16-row instructions)
  const int sr = w * 32 + (lane >> 2);       // global row for inst 0
  const int sc = (lane & 3) * 8;             // u16 col offset within 32-wide tile
  const u16* gA0 = A  + (size_t)(bm + sr) * lda + sc;
  const u16* gA1 = A  + (size_t)(bm + sr + 16) * lda + sc;
  const u16* gB0 = BT + (size_t)(bn + sr) * K + sc;
  const u16* gB1 = BT + (size_t)(bn + sr + 16) * K + sc;
  u16* lA0 = &As[w * 32][0];
  u16* lA1 = &As[w * 32 + 16][0];
  u16* lB0 = &Bs[w * 32][0];
  u16* lB1 = &Bs[w * 32 + 16][0];
  for (int ks = 0; ks < K; ks += 32) {
    __syncthreads();   // prev-iter readers done before LDS overwrite
    gload_lds16(gA0 + ks, lA0);
    gload_lds16(gA1 + ks, lA1);
    gload_lds16(gB0 + ks, lB0);
    gload_lds16(gB1 + ks, lB1);
    __syncthreads();   // compiler drains vmcnt(0) before barrier
    bf16x8 af[4], bf[4];
#pragma unroll
    for (int i = 0; i < 4; i++) af[i] = *(const bf16x8*)&As[wr + i * 16 + r][quad * 8];
#pragma unroll
    for (int j = 0; j < 4; j++) bf[j] = *(const bf16x8*)&Bs[wc + j * 16 + r][quad * 8];
#pragma unroll
    for (int i = 0; i < 4; i++)
#pragma unroll
      for (int j = 0; j < 4; j++)
        acc[i][j] = __builtin_amdgcn_mfma_f32_16x16x32_bf16(af[i], bf[j], acc[i][j], 0, 0, 0);
  }
  // fused L2-norm: wave quadrant = one 64-col head; per row d = j*16 + r.
  // prep's butterfly (off 32,16,8,4,2,1 on d) == reg pairs (j^2 then j^1)
  // then shfl_xor 8,4,2,1 (all within the 16-lane quad group = one row).
  int mode = 0;
  if (do_norm) { if (blockIdx.y < 8) mode = 1; else if (blockIdx.y < 24) mode = 2; }
  if (mode) {
#pragma unroll
    for (int i = 0; i < 4; i++)
#pragma unroll
      for (int rg = 0; rg < 4; rg++) {
        float a0 = acc[i][0][rg], a1 = acc[i][1][rg];
        float a2 = acc[i][2][rg], a3 = acc[i][3][rg];
        float ss = (a0 * a0 + a2 * a2) + (a1 * a1 + a3 * a3);
        ss += __shfl_xor(ss, 8);
        ss += __shfl_xor(ss, 4);
        ss += __shfl_xor(ss, 2);
        ss += __shfl_xor(ss, 1);
        float rs = rsqrtf(ss + 1e-6f);
#pragma unroll
        for (int j = 0; j < 4; j++) {
          float ov = acc[i][j][rg] * rs;
          if (mode == 1) ov *= 0.125f;
          acc[i][j][rg] = ov;
        }
      }
  }
  // fused beta/g: by==40, wc=0 quadrants hold cols 5120+j*16+r.
  // j=0 -> beta nh=0 (h=r), j=1 -> beta nh=1, j=2 -> a-pre. acc fp32 ==
  // the P value the old prep_bg kernel re-read -> bit-exact.
  if (do_norm && blockIdx.y == 40 && (w & 1) == 0) {
    const float al = A_log[r], db = dt_bias[r];
#pragma unroll
    for (int i = 0; i < 4; i++)
#pragma unroll
      for (int rg = 0; rg < 4; rg++) {
        int t = bm + wr + i * 16 + quad * 4 + rg;
        float b0 = acc[i][0][rg], b1 = acc[i][1][rg];
        betab[(size_t)(2 * t) * 16 + r]     = 2.f / (1.f + expf(-b0));
        betab[(size_t)(2 * t + 1) * 16 + r] = 2.f / (1.f + expf(-b1));
        float a = acc[i][2][rg] + db;
        float sp = (a > 20.f) ? a : log1pf(expf(a));
        gbuf[t * 16 + r] = -expf(al) * sp;
      }
  }
#pragma unroll
  for (int i = 0; i < 4; i++)
#pragma unroll
    for (int j = 0; j < 4; j++)
#pragma unroll
      for (int rg = 0; rg < 4; rg++) {
        int row = bm + wr + i * 16 + quad * 4 + rg;
        int col = bn + wc + j * 16 + r;
        if (col < Nmax) {
          float v = acc[i][j][rg];
          if (out_bf16) Cb[(size_t)row * ldc + col] = f2bf(v);
          else          Cf[(size_t)row * ldc + col] = v;
        }
      }
}

// 64x128-tile GEMM for the output projection: 2 waves, 256 blocks (1/CU).
// Same per-output mfma K-chain as gemm128 (bit-exact).
__global__ __launch_bounds__(128) void gemm64(const u16* __restrict__ A,
    const u16* __restrict__ BT, float* __restrict__ C, int K, int lda, int ldc) {
  const int bm = blockIdx.x * 64, bn = blockIdx.y * 128;
  const int tid = threadIdx.x, w = tid >> 6, lane = tid & 63;
  const int wc = w * 64;
  const int quad = lane >> 4, r = lane & 15;
  __shared__ u16 As[64][32], Bs[128][32];
  f32x4 acc[4][4] = {};
  const int lr = lane >> 2;          // staging row within 16-row group
  const int sc = (lane & 3) * 8;
  for (int ks = 0; ks < K; ks += 32) {
    __syncthreads();
    if (w == 0) {
      gload_lds16(A  + (size_t)(bm +  0 + lr) * lda + ks + sc, &As[0][0]);
      gload_lds16(A  + (size_t)(bm + 16 + lr) * lda + ks + sc, &As[16][0]);
      gload_lds16(A  + (size_t)(bm + 32 + lr) * lda + ks + sc, &As[32][0]);
      gload_lds16(A  + (size_t)(bm + 48 + lr) * lda + ks + sc, &As[48][0]);
      gload_lds16(BT + (size_t)(bn +  0 + lr) * K + ks + sc, &Bs[0][0]);
      gload_lds16(BT + (size_t)(bn + 16 + lr) * K + ks + sc, &Bs[16][0]);
    } else {
      gload_lds16(BT + (size_t)(bn +  32 + lr) * K + ks + sc, &Bs[32][0]);
      gload_lds16(BT + (size_t)(bn +  48 + lr) * K + ks + sc, &Bs[48][0]);
      gload_lds16(BT + (size_t)(bn +  64 + lr) * K + ks + sc, &Bs[64][0]);
      gload_lds16(BT + (size_t)(bn +  80 + lr) * K + ks + sc, &Bs[80][0]);
      gload_lds16(BT + (size_t)(bn +  96 + lr) * K + ks + sc, &Bs[96][0]);
      gload_lds16(BT + (size_t)(bn + 112 + lr) * K + ks + sc, &Bs[112][0]);
    }
    __syncthreads();
    bf16x8 af[4], bf[4];
#pragma unroll
    for (int i = 0; i < 4; i++) af[i] = *(const bf16x8*)&As[i * 16 + r][quad * 8];
#pragma unroll
    for (int j = 0; j < 4; j++) bf[j] = *(const bf16x8*)&Bs[wc + j * 16 + r][quad * 8];
#pragma unroll
    for (int i = 0; i < 4; i++)
#pragma unroll
      for (int j = 0; j < 4; j++)
        acc[i][j] = __builtin_amdgcn_mfma_f32_16x16x32_bf16(af[i], bf[j], acc[i][j], 0, 0, 0);
  }
#pragma unroll
  for (int i = 0; i < 4; i++)
#pragma unroll
    for (int j = 0; j < 4; j++)
#pragma unroll
      for (int rg = 0; rg < 4; rg++)
        C[(size_t)(bm + i * 16 + quad * 4 + rg) * ldc + bn + wc + j * 16 + r] = acc[i][j][rg];
}

// phase A: per (c,h): G, T, W(bf16), M(fp32), Uv(bf16), NT(fp32), cum.
// 3 LDS arrays (53248 B -> 3 blocks/CU): LA: kT->Tt->Uv, LB: kf, LC: Sc->v->W.
// r13 structure; k/v staging vectorized to f32x4 (same values/destinations).
__global__ __launch_bounds__(256, 1) void phaseA_kernel(const float* __restrict__ P,
    const float* __restrict__ betab, const float* __restrict__ gbuf,
    u16* __restrict__ Wbuf, u16* __restrict__ Uvbuf,
    float* __restrict__ Mbuf, float* __restrict__ NTbuf, float* __restrict__ cumbuf) {
  const int c = blockIdx.x, h = blockIdx.y, tid = threadIdx.x;
  const int bi = tid >> 4, bj = tid & 15;
  __shared__ float LA[64][68];   // kT -> Tt -> Uv
  __shared__ float LB[64][68];   // kf (persistent)
  __shared__ float LC[64][68];   // Sc -> v -> W
  __shared__ float cumch[64], betach[64], bbch[64], rowfl[64];
  const size_t base = ((size_t)c * 16 + h) * 4096;
  const int rq = tid >> 4, dq = (tid & 15) * 4;   // f32x4 staging map

  {
#pragma unroll
    for (int s = 0; s < 4; s++) {
      int i = rq + 16 * s, sg = c * 64 + i, t = sg >> 1, nh = sg & 1;
      f32x4 kv = *(const f32x4*)&P[(size_t)t * NP + 1024 + nh * 1024 + h * 64 + dq];
      *(f32x4*)&LB[i][dq] = kv;
      LA[dq + 0][i] = kv[0];
      LA[dq + 1][i] = kv[1];
      LA[dq + 2][i] = kv[2];
      LA[dq + 3][i] = kv[3];
    }
  }
  if (tid < 64) betach[tid] = betab[(size_t)(c * 64 + tid) * 16 + h];
  __syncthreads();
  if (tid == 0) {
    float cum = 0.f;
    for (int i = 0; i < 64; i++) {
      if ((i & 1) == 0) cum += gbuf[(c * 32 + (i >> 1)) * 16 + h];
      cumch[i] = cum;
    }
  }
  __syncthreads();
  if (tid < 64) {
    bbch[tid] = betach[tid] * expf(cumch[tid]);
    rowfl[tid] = expf(cumch[63] - cumch[tid]);
  }
  // G then scale -> LC
  {
    float acc[4][4] = {};
#pragma unroll 4
    for (int d = 0; d < 64; d++) {
      f32x4 a = *(const f32x4*)&LA[d][4 * bi];
      f32x4 b = *(const f32x4*)&LA[d][4 * bj];
#pragma unroll
      for (int rr = 0; rr < 4; rr++)
#pragma unroll
        for (int cc = 0; cc < 4; cc++) acc[rr][cc] += a[rr] * b[cc];
    }
#pragma unroll
    for (int rr = 0; rr < 4; rr++)
#pragma unroll
      for (int cc = 0; cc < 4; cc++) {
        int i = 4 * bi + rr, j = 4 * bj + cc;
        LC[i][j] = (j < i) ? betach[i] * expf(cumch[i] - cumch[j]) * acc[rr][cc] : 0.f;
      }
  }
  __syncthreads();
  // T = (I+A)^-1 forward substitution: LC(Sc) -> LA[j][i] (Tt)
  {
    int col = tid >> 2, part = tid & 3;
    if (part == 0) LA[col][0] = (col == 0) ? 1.f : 0.f;
    for (int i = 1; i < 64; i++) {
      float partial = 0.f;
      for (int j = col + part; j < i; j += 4) partial += LC[i][j] * LA[col][j];
      partial += __shfl_xor(partial, 1);
      partial += __shfl_xor(partial, 2);
      if (part == 0) LA[col][i] = ((i == col) ? 1.f : 0.f) - partial;
    }
  }
  __syncthreads();
  // prefetch v into regs now (f32x4); ds_write after M (hides under W+M)
  f32x4 vreg4[4];
  {
#pragma unroll
    for (int s = 0; s < 4; s++) {
      int i = rq + 16 * s, sg = c * 64 + i, t = sg >> 1, nh = sg & 1;
      vreg4[s] = *(const f32x4*)&P[(size_t)t * NP + 3072 + nh * 1024 + h * 64 + dq];
    }
  }
  // W[i][d] = sum_{j<=i} T[i][j]*bb[j]*k[j][d]  (triangular trip)
  {
    float acc[4][4] = {};
#pragma unroll 4
    for (int j = 0; j < 4 * bi + 4; j++) {
      f32x4 tv = *(const f32x4*)&LA[j][4 * bi];
      f32x4 kv = *(const f32x4*)&LB[j][4 * bj];
      float bbj = bbch[j];
#pragma unroll
      for (int rr = 0; rr < 4; rr++)
#pragma unroll
        for (int cc = 0; cc < 4; cc++) acc[rr][cc] += tv[rr] * bbj * kv[cc];
    }
#pragma unroll
    for (int rr = 0; rr < 4; rr++) {
      int i = 4 * bi + rr;
      u16x4 wb;
#pragma unroll
      for (int cc = 0; cc < 4; cc++) { LC[i][4 * bj + cc] = acc[rr][cc]; wb[cc] = f2bf(acc[rr][cc]); }
      *(u16x4*)&Wbuf[base + (size_t)i * 64 + 4 * bj] = wb;
    }
  }
  __syncthreads();
  // M[m][mm] = bL*delta - sum_i rowf[i]*k[i][m]*W[i][mm]
  {
    const float bL = expf(cumch[63]);
    float acc[4][4] = {};
#pragma unroll 4
    for (int i = 0; i < 64; i++) {
      f32x4 kv = *(const f32x4*)&LB[i][4 * bi];
      f32x4 wv = *(const f32x4*)&LC[i][4 * bj];
      float rf = rowfl[i];
#pragma unroll
      for (int rr = 0; rr < 4; rr++)
#pragma unroll
        for (int cc = 0; cc < 4; cc++) acc[rr][cc] += rf * kv[rr] * wv[cc];
    }
#pragma unroll
    for (int rr = 0; rr < 4; rr++) {
      int m = 4 * bi + rr;
      f32x4 mv;
#pragma unroll
      for (int cc = 0; cc < 4; cc++)
        mv[cc] = ((m == 4 * bj + cc) ? bL : 0.f) - acc[rr][cc];
      *(f32x4*)&Mbuf[base + (size_t)m * 64 + 4 * bj] = mv;
    }
  }
  __syncthreads();
  // stage v (from regs) over LC
  {
#pragma unroll
    for (int s = 0; s < 4; s++) *(f32x4*)&LC[rq + 16 * s][dq] = vreg4[s];
  }
  __syncthreads();
  // Uv[i][d] = sum_{j<=i} T[i][j]*beta[j]*v[j][d] -> regs (LA still = Tt)
  float ua[4][4] = {};
  {
#pragma unroll 4
    for (int j = 0; j < 4 * bi + 4; j++) {
      f32x4 tv = *(const f32x4*)&LA[j][4 * bi];
      f32x4 vv = *(const f32x4*)&LC[j][4 * bj];
      float be = betach[j];
#pragma unroll
      for (int rr = 0; rr < 4; rr++)
#pragma unroll
        for (int cc = 0; cc < 4; cc++) ua[rr][cc] += tv[rr] * be * vv[cc];
    }
  }
  __syncthreads();   // all Tt reads complete before overwrite
  {
#pragma unroll
    for (int rr = 0; rr < 4; rr++) {
      int i = 4 * bi + rr;
      u16x4 ub;
#pragma unroll
      for (int cc = 0; cc < 4; cc++) { LA[i][4 * bj + cc] = ua[rr][cc]; ub[cc] = f2bf(ua[rr][cc]); }
      *(u16x4*)&Uvbuf[base + (size_t)i * 64 + 4 * bj] = ub;
    }
  }
  __syncthreads();
  // NT[d][m] = sum_i rowf[i]*k[i][m]*Uv[i][d]
  {
    float acc[4][4] = {};
#pragma unroll 4
    for (int i = 0; i < 64; i++) {
      f32x4 kv = *(const f32x4*)&LB[i][4 * bi];
      f32x4 uv = *(const f32x4*)&LA[i][4 * bj];
      float rf = rowfl[i];
#pragma unroll
      for (int rr = 0; rr < 4; rr++)
#pragma unroll
        for (int cc = 0; cc < 4; cc++) acc[rr][cc] += rf * kv[rr] * uv[cc];
    }
#pragma unroll
    for (int cc = 0; cc < 4; cc++) {
      f32x4 nv;
#pragma unroll
      for (int rr = 0; rr < 4; rr++) nv[rr] = acc[rr][cc];
      *(f32x4*)&NTbuf[base + (size_t)(4 * bj + cc) * 64 + 4 * bi] = nv;
    }
  }
  if (tid < 64) cumbuf[((size_t)c * 16 + h) * 64 + tid] = cumch[tid];
}

// phase B v2 (r21): 4 cols/block, 2 waves; M chunk staged once into LDS
// (dbuf, pad-68) and shared by both waves -> 256 blocks (1/CU), 256MB M
// traffic. Per-column math/order identical to r13 (bit-exact).
__global__ __launch_bounds__(128) void phaseB_kernel(const float* __restrict__ Mbuf,
    const float* __restrict__ NTbuf, u16* __restrict__ S0Tbuf) {
  const int g = blockIdx.x, h = blockIdx.y;
  const int tid = threadIdx.x, wv = tid >> 6, l = tid & 63;
  const int c0 = 4 * g + 2 * wv, c1 = c0 + 1;
  __shared__ float Ms[2][64][68];
  __shared__ float Ssh[2][4][64];
  float s0 = 0.f, s1 = 0.f;
  float n0, n1;
  f32x4 mn[8];
  // stage chunk 0: thread t covers f32x4-slots t*8..t*8+7 (row=slot>>4, s=slot&15)
  {
    const float* Mc = Mbuf + (size_t)h * 4096;
#pragma unroll
    for (int i = 0; i < 8; i++) {
      int sl = tid * 8 + i;
      mn[i] = *(const f32x4*)(Mc + (sl >> 4) * 64 + (sl & 15) * 4);
    }
#pragma unroll
    for (int i = 0; i < 8; i++) {
      int sl = tid * 8 + i;
      *(f32x4*)&Ms[0][sl >> 4][(sl & 15) * 4] = mn[i];
    }
    const float* Nc = NTbuf + (size_t)h * 4096;
    n0 = Nc[c0 * 64 + l]; n1 = Nc[c1 * 64 + l];
  }
  Ssh[0][2 * wv][l] = 0.f; Ssh[0][2 * wv + 1][l] = 0.f;
  __syncthreads();
  int p = 0;
  for (int c = 0; c < NC; c++) {
    const size_t base = ((size_t)c * 16 + h) * 4096;
    S0Tbuf[base + (size_t)c0 * 64 + l] = f2bf(s0);
    S0Tbuf[base + (size_t)c1 * 64 + l] = f2bf(s1);
    float nn0 = 0.f, nn1 = 0.f;
    if (c + 1 < NC) {
      // issue next-chunk M loads (latency hides under compute below)
      const float* Mn = Mbuf + ((size_t)(c + 1) * 16 + h) * 4096;
#pragma unroll
      for (int i = 0; i < 8; i++) {
        int sl = tid * 8 + i;
        mn[i] = *(const f32x4*)(Mn + (sl >> 4) * 64 + (sl & 15) * 4);
      }
      const float* Nn = NTbuf + ((size_t)(c + 1) * 16 + h) * 4096;
      nn0 = Nn[c0 * 64 + l]; nn1 = Nn[c1 * 64 + l];
    }
    float acc0 = n0, acc1 = n1;
#pragma unroll
    for (int q = 0; q < 16; q++) {
      f32x4 mv = *(const f32x4*)&Ms[p][l][4 * q];
      f32x4 sv0 = *(const f32x4*)&Ssh[p][2 * wv][4 * q];
      f32x4 sv1 = *(const f32x4*)&Ssh[p][2 * wv + 1][4 * q];
#pragma unroll
      for (int t = 0; t < 4; t++) { acc0 += mv[t] * sv0[t]; acc1 += mv[t] * sv1[t]; }
    }
    s0 = acc0; s1 = acc1;
    Ssh[p ^ 1][2 * wv][l] = s0; Ssh[p ^ 1][2 * wv + 1][l] = s1;
    if (c + 1 < NC) {
#pragma unroll
      for (int i = 0; i < 8; i++) {
        int sl = tid * 8 + i;
        *(f32x4*)&Ms[p ^ 1][sl >> 4][(sl & 15) * 4] = mn[i];
      }
    }
    __syncthreads();
    p ^= 1;
    n0 = nn0; n1 = nn1;
  }
}

// phase C (with phaseB2 fused in):
//   kTc: k -> S0 ; Ul: W^T -> U (U = Uv - W*S0). pass2 byte-identical.
//   T14 async-stage: S0/W prefetched before pass1, Uv before B2, gate
//   before the ol barrier (same values/destinations -> bit-exact).
__global__ __launch_bounds__(256) void phaseC_kernel(const float* __restrict__ P,
    const float* __restrict__ cumbuf, const u16* __restrict__ Wbuf,
    const u16* __restrict__ Uvbuf, const u16* __restrict__ S0Tbuf,
    const float* __restrict__ nw, u16* __restrict__ ybuf) {
  const int c = blockIdx.x, h = blockIdx.y, tid = threadIdx.x;
  const int rb = tid >> 4, jb = tid & 15;
  __shared__ float qT[64][36];    // [d][r]; reused as ol[32][68]
  __shared__ float kTc[64][68];   // k[d][j] -> S0l[m][d]
  __shared__ float Ul[64][68];    // WTl[m][i] -> U[j][d]
  __shared__ float PmT[64][36];
  __shared__ float cuml[64], nwl[64];
  const size_t base = (size_t)c * 16 + h;
  for (int c4 = tid; c4 < 512; c4 += 256) {
    int e = c4 * 4, r = e >> 6, d = e & 63;
    f32x4 qv = *(const f32x4*)&P[(size_t)(c * 32 + r) * NP + h * 64 + d];
    qT[d][r] = qv[0]; qT[d + 1][r] = qv[1]; qT[d + 2][r] = qv[2]; qT[d + 3][r] = qv[3];
  }
  for (int c4 = tid; c4 < 1024; c4 += 256) {
    int e = c4 * 4, j = e >> 6, d = e & 63, sg = c * 64 + j, t = sg >> 1, nh = sg & 1;
    f32x4 kv = *(const f32x4*)&P[(size_t)t * NP + 1024 + nh * 1024 + h * 64 + d];
    kTc[d][j] = kv[0]; kTc[d + 1][j] = kv[1]; kTc[d + 2][j] = kv[2]; kTc[d + 3][j] = kv[3];
  }
  if (tid < 64) { cuml[tid] = cumbuf[base * 64 + tid]; nwl[tid] = nw[tid]; }
  // ---- T14: issue S0/W loads now; consumed after pass1 ----
  u16x4 s0p[4], wp[4];
#pragma unroll
  for (int s = 0; s < 4; s++) {
    int e = (tid + 256 * s) * 4;
    s0p[s] = *(const u16x4*)&S0Tbuf[base * 4096 + e];
    wp[s]  = *(const u16x4*)&Wbuf[base * 4096 + e];
  }
  __syncthreads();
  // ---- pass1: QK^T -> PmT ----
  {
    float pa[2][4] = {};
#pragma unroll 4
    for (int d = 0; d < 64; d++) {
      f32x2 qv = *(const f32x2*)&qT[d][2 * rb];
      f32x4 kv = *(const f32x4*)&kTc[d][4 * jb];
#pragma unroll
      for (int rr = 0; rr < 2; rr++)
#pragma unroll
        for (int cc = 0; cc < 4; cc++) pa[rr][cc] += qv[rr] * kv[cc];
    }
#pragma unroll
    for (int rr = 0; rr < 2; rr++)
#pragma unroll
      for (int cc = 0; cc < 4; cc++) {
        int r = 2 * rb + rr, i = 2 * r + 1, j = 4 * jb + cc;
        PmT[j][r] = (j <= i) ? expf(cuml[i] - cuml[j]) * pa[rr][cc] : 0.f;
      }
  }
  __syncthreads();
  // ---- stage2 (from prefetched regs): kTc <- S0, Ul <- W^T ----
#pragma unroll
  for (int s = 0; s < 4; s++) {
    int e = (tid + 256 * s) * 4, i = e >> 6, m = e & 63;
    kTc[m][i] = bf2f(s0p[s][0]); kTc[m + 1][i] = bf2f(s0p[s][1]);
    kTc[m + 2][i] = bf2f(s0p[s][2]); kTc[m + 3][i] = bf2f(s0p[s][3]);
    Ul[m][i] = bf2f(wp[s][0]); Ul[m + 1][i] = bf2f(wp[s][1]);
    Ul[m + 2][i] = bf2f(wp[s][2]); Ul[m + 3][i] = bf2f(wp[s][3]);
  }
  // ---- T14: issue Uv loads now; consumed after B2 ----
  u16x4 uvp[4];
#pragma unroll
  for (int rr = 0; rr < 4; rr++)
    uvp[rr] = *(const u16x4*)&Uvbuf[base * 4096 + (size_t)(4 * rb + rr) * 64 + 4 * jb];
  __syncthreads();
  // ---- B2 compute: acc = W*S0 ----
  float b2acc[4][4] = {};
  {
#pragma unroll 4
    for (int m = 0; m < 64; m++) {
      f32x4 wv = *(const f32x4*)&Ul[m][4 * rb];
      f32x4 sv = *(const f32x4*)&kTc[m][4 * jb];
#pragma unroll
      for (int rr = 0; rr < 4; rr++)
#pragma unroll
        for (int cc = 0; cc < 4; cc++) b2acc[rr][cc] += wv[rr] * sv[cc];
    }
  }
  __syncthreads();   // W^T reads done before U overwrite
  // ---- U write into Ul (from prefetched Uv) ----
#pragma unroll
  for (int rr = 0; rr < 4; rr++) {
    int i = 4 * rb + rr;
#pragma unroll
    for (int cc = 0; cc < 4; cc++)
      Ul[i][4 * jb + cc] = bf2f(f2bf(bf2f(uvp[rr][cc]) - b2acc[rr][cc]));
  }
  __syncthreads();
  // ---- pass2 ----
  float o[2][4];
  {
    float a1[2][4] = {}, a2[2][4] = {};
#pragma unroll 4
    for (int m = 0; m < 64; m++) {
      f32x2 qv = *(const f32x2*)&qT[m][2 * rb];
      f32x4 sv = *(const f32x4*)&kTc[m][4 * jb];
#pragma unroll
      for (int rr = 0; rr < 2; rr++)
#pragma unroll
        for (int cc = 0; cc < 4; cc++) a1[rr][cc] += qv[rr] * sv[cc];
    }
    // triangular: PmT[j][r]=0 for j>2r+1; max needed j = 4rb+3
#pragma unroll 4
    for (int j = 0; j < 4 * rb + 4; j++) {
      f32x2 pv = *(const f32x2*)&PmT[j][2 * rb];
      f32x4 uv = *(const f32x4*)&Ul[j][4 * jb];
#pragma unroll
      for (int rr = 0; rr < 2; rr++)
#pragma unroll
        for (int cc = 0; cc < 4; cc++) a2[rr][cc] += pv[rr] * uv[cc];
    }
#pragma unroll
    for (int rr = 0; rr < 2; rr++) {
      float ec = expf(cuml[2 * (2 * rb + rr) + 1]);
#pragma unroll
      for (int cc = 0; cc < 4; cc++) o[rr][cc] = a1[rr][cc] * ec + a2[rr][cc];
    }
  }
  // ---- T14: issue gate loads now; consumed in the final loop ----
  float gtp[8];
#pragma unroll
  for (int s = 0; s < 8; s++) {
    int e = tid + 256 * s, r = e >> 6, d = e & 63;
    gtp[s] = P[(size_t)(c * 32 + r) * NP + 5168 + h * 64 + d];
  }
  __syncthreads();
  float* ol = &qT[0][0];   // [32][68]
#pragma unroll
  for (int rr = 0; rr < 2; rr++)
#pragma unroll
    for (int cc = 0; cc < 4; cc++)
      ol[(2 * rb + rr) * 68 + 4 * jb + cc] = o[rr][cc];
  __syncthreads();
#pragma unroll
  for (int s = 0; s < 8; s++) {
    int e = tid + 256 * s, r = e >> 6, d = e & 63;
    float ov = ol[r * 68 + d];
    float ss = ov * ov;
#pragma unroll
    for (int off = 32; off; off >>= 1) ss += __shfl_xor(ss, off);
    float on = ov * rsqrtf(ss * (1.f / 64.f) + 1e-5f) * nwl[d];
    int t = c * 32 + r;
    float gt = gtp[s];
    float sw = gt / (1.f + expf(-gt));
    ybuf[(size_t)t * 1024 + h * 64 + d] = f2bf(on * sw);
  }
}

extern "C" void kernel_launch(void* const* d_in, const int* in_sizes, int n_in,
                              void* d_out, int out_size, void* d_ws, size_t ws_size,
                              hipStream_t stream) {
  const float* x       = (const float*)d_in[0];
  const float* Wq      = (const float*)d_in[1];
  const float* Wk      = (const float*)d_in[2];
  const float* Wv      = (const float*)d_in[3];
  const float* Wb      = (const float*)d_in[4];
  const float* Wa      = (const float*)d_in[5];
  const float* A_log   = (const float*)d_in[6];
  const float* dt_bias = (const float*)d_in[7];
  const float* Wg      = (const float*)d_in[8];
  const float* nw      = (const float*)d_in[9];
  const float* Wo      = (const float*)d_in[10];
  float* out = (float*)d_out;

  char* w = (char*)d_ws;
  size_t used = 0;
  auto alloc = [&](size_t bytes) {
    char* p = w + used; used += (bytes + 255) & ~(size_t)255; return p;
  };
  u16*   xb    = (u16*)  alloc(2048UL * 1024 * 2);
  u16*   WT    = (u16*)  alloc(6272UL * 1024 * 2);   // padded to 49*128 rows
  u16*   WoT   = (u16*)  alloc(1024UL * 1024 * 2);
  float* P     = (float*)alloc(2048UL * NP * 4);
  float* betab = (float*)alloc(4096UL * 16 * 4);
  float* gbuf  = (float*)alloc(2048UL * 16 * 4);
  u16*   ybuf  = (u16*)  alloc(2048UL * 1024 * 2);
  u16*   Wbuf  = (u16*)  alloc((size_t)NC * 16 * 4096 * 2);
  u16*   Uvbuf = (u16*)  alloc((size_t)NC * 16 * 4096 * 2);
  u16*   S0Tb  = (u16*)  alloc((size_t)NC * 16 * 4096 * 2);
  float* Mbuf  = (float*)alloc((size_t)NC * 16 * 4096 * 4);
  float* NTbuf = (float*)alloc((size_t)NC * 16 * 4096 * 4);
  float* cumb  = (float*)alloc((size_t)NC * 16 * 64 * 4);

  auto tgrid = [](long n) { return dim3((unsigned)((n + 255) / 256)); };
  if (used > ws_size) {
    beacon_kernel<<<tgrid(out_size), 256, 0, stream>>>(out, out_size);
    return;
  }

  // zero pad rows 6192..6271 (edge tile of the 128-wide gemm reads them)
  hipMemsetAsync(WT + 6192UL * 1024, 0, 80UL * 1024 * 2, stream);

  // weights transpose+convert + x conversion in one launch
  transAll_kernel<<<dim3(290, 32), 256, 0, stream>>>(Wq, Wk, Wv, Wb, Wa, Wg, Wo, WT, WoT, x, xb);

  // P (fp32) = xb @ [Wq|Wk|Wv|Wb|Wa|Wg]; q/k norm + beta/g fused in epilogue
  gemm128<<<dim3(16, 49), 256, 0, stream>>>(xb, WT, P, nullptr, 1024, 1024, NP, NP, 0, 1,
                                            A_log, dt_bias, betab, gbuf);

  phaseA_kernel<<<dim3(NC, 16), 256, 0, stream>>>(P, betab, gbuf, Wbuf, Uvbuf, Mbuf, NTbuf, cumb);
  phaseB_kernel<<<dim3(16, 16), 128, 0, stream>>>(Mbuf, NTbuf, S0Tb);
  phaseC_kernel<<<dim3(NC, 16), 256, 0, stream>>>(P, cumb, Wbuf, Uvbuf, S0Tb, nw, ybuf);

  // out (fp32) = ybuf @ Wo (64x128 tiles: 256 blocks = 1/CU)
  gemm64<<<dim3(32, 8), 128, 0, stream>>>(ybuf, WoT, out, 1024, 1024, 1024);
}